// Round 6
// baseline (517.636 us; speedup 1.0000x reference)
//
#include <hip/hip_runtime.h>
#include <cstdint>
#include <cstddef>

typedef __bf16 bf16;
typedef __bf16 bf16x4 __attribute__((ext_vector_type(4)));
typedef __bf16 bf16x8 __attribute__((ext_vector_type(8)));
typedef float  f32x4  __attribute__((ext_vector_type(4)));
typedef short  s16x4  __attribute__((ext_vector_type(4)));

#define HIDDEN 2048
#define NHEADS 16
#define HDIM   128
#define BSZ    2
#define SEQ    2048
#define BS     (BSZ*SEQ)     /* 4096 rows */
#define QKW    (2*HIDDEN)    /* 4096: Q|K concat width */

union b4u { bf16x4 h; s16x4 s; };

// async global->LDS, 16B per lane. LDS dest = wave-uniform base + lane*16.
__device__ __forceinline__ void async16(const bf16* g, bf16* l) {
    __builtin_amdgcn_global_load_lds(
        (const __attribute__((address_space(1))) unsigned int*)g,
        (__attribute__((address_space(3))) unsigned int*)l, 16, 0, 0);
}

#define BARX()  asm volatile("s_barrier" ::: "memory")
#define VMW(N)  asm volatile("s_waitcnt vmcnt(" #N ")" ::: "memory")

// raw v_exp_f32: exp2 is the native op, skip OCML fixups (args are <= 8, large-neg -> 0)
__device__ __forceinline__ float ex2(float x) {
    float r; asm("v_exp_f32 %0, %1" : "=v"(r) : "v"(x)); return r;
}

// ---------------------------------------------------------------- fused casts + rope table
__global__ __launch_bounds__(256) void cast_all(const float* __restrict__ hs,
                                                const float* __restrict__ Wq,
                                                const float* __restrict__ Wk,
                                                const float* __restrict__ Wv,
                                                const float* __restrict__ Wo,
                                                const int* __restrict__ pos,
                                                bf16* __restrict__ hs_b,
                                                bf16* __restrict__ wqkv,
                                                bf16* __restrict__ wo_b,
                                                float2* __restrict__ tab) {
    int i = blockIdx.x * 256 + threadIdx.x;
    if (i >= 6291456) {                       // rope table region
        int j = i - 6291456;                  // 0..131071
        int s = j >> 6, p = j & 63;
        float t = (float)pos[s];
        float inv = expf(-(float)(2 * p) * (9.2103403719761836f / 128.0f));
        float sn, cs;
        sincosf(t * inv, &sn, &cs);
        tab[j] = make_float2(cs, sn);
        return;
    }
    const float* src; bf16* dst; int off;
    if (i < 2097152) { src = hs; dst = hs_b; off = i; }
    else {
        int j = i - 2097152;
        int r = j >> 20;
        off = j & 1048575;
        if      (r == 0) { src = Wq; dst = wqkv; }
        else if (r == 1) { src = Wk; dst = wqkv + (size_t)4194304; }
        else if (r == 2) { src = Wv; dst = wqkv + (size_t)8388608; }
        else             { src = Wo; dst = wo_b; }
    }
    const float4 v = ((const float4*)src)[off];
    bf16x4 o;
    o.x = (bf16)v.x; o.y = (bf16)v.y; o.z = (bf16)v.z; o.w = (bf16)v.w;
    ((bf16x4*)dst)[off] = o;
}

// ---------------------------------------------------------------- Q|K GEMM + RoPE
// 256x256 tile, BK=32, 512 thr (8 waves 2M x 4N), ring-4 LDS, counted vmcnt,
// st_16x32 swizzle, setprio. Grid 256 = EXACTLY one full round on 256 CUs.
// Q region written PRE-SCALED by 1/sqrt(128)*log2(e) so attn's S is exp2-domain.
__device__ __forceinline__ int qk_perm(int n) {
    int wl = n >> 6, j = n & 63;
    return ((wl >> 1) << 7) | ((j >> 5) << 6) | ((wl & 1) << 5) | (j & 31);
}

#define QKV_TILE(T, DOSTAGE, VMN) do {                                          \
    VMW(VMN);                                                                   \
    BARX();                                                                     \
    const bf16* lAr = lA0 + ((T) & 3) * 16384;                                  \
    const bf16* lBr = lB0 + ((T) & 3) * 16384;                                  \
    bf16x8 bfr[4], af[4];                                                       \
    _Pragma("unroll") for (int nf = 0; nf < 4; ++nf)                            \
        bfr[nf] = *(const bf16x8*)(lBr + nf * 512);                             \
    _Pragma("unroll") for (int mf = 0; mf < 4; ++mf)                            \
        af[mf] = *(const bf16x8*)(lAr + mf * 512);                              \
    if (DOSTAGE) {                                                              \
        bf16* dA = smem + (((T) + 3) & 3) * 16384 + w * 512;                    \
        async16(pa0 + ((T) + 3) * 32, dA);                                      \
        async16(pa1 + ((T) + 3) * 32, dA + 4096);                               \
    }                                                                           \
    __builtin_amdgcn_s_setprio(1);                                              \
    _Pragma("unroll") for (int mf = 0; mf < 4; ++mf)                            \
    _Pragma("unroll") for (int nf = 0; nf < 4; ++nf)                            \
        acc[mf][nf] = __builtin_amdgcn_mfma_f32_16x16x32_bf16(                  \
            af[mf], bfr[nf], acc[mf][nf], 0, 0, 0);                             \
    __builtin_amdgcn_s_setprio(0);                                              \
    _Pragma("unroll") for (int mf = 0; mf < 4; ++mf)                            \
        af[mf] = *(const bf16x8*)(lAr + 2048 + mf * 512);                       \
    if (DOSTAGE) {                                                              \
        bf16* dB = smem + (((T) + 3) & 3) * 16384 + 8192 + w * 512;             \
        async16(pb0 + ((T) + 3) * 32, dB);                                      \
        async16(pb1 + ((T) + 3) * 32, dB + 4096);                               \
    }                                                                           \
    __builtin_amdgcn_s_setprio(1);                                              \
    _Pragma("unroll") for (int mf = 0; mf < 4; ++mf)                            \
    _Pragma("unroll") for (int nf = 0; nf < 4; ++nf)                            \
        acc[4 + mf][nf] = __builtin_amdgcn_mfma_f32_16x16x32_bf16(              \
            af[mf], bfr[nf], acc[4 + mf][nf], 0, 0, 0);                         \
    __builtin_amdgcn_s_setprio(0);                                              \
} while (0)

__global__ __launch_bounds__(512, 2) void gemm_qk(const bf16* __restrict__ A,
                                                  const bf16* __restrict__ Bt,
                                                  const float2* __restrict__ tab,
                                                  bf16* __restrict__ qk) {
    __shared__ alignas(16) bf16 smem[65536];   // 128 KiB: 4 bufs x (A 8192 | B 8192)

    const int tid  = threadIdx.x;
    const int lane = tid & 63;
    const int w    = tid >> 6;
    const int l15  = lane & 15;
    const int quad = lane >> 4;
    const int wm   = w >> 2;       // 0..1
    const int wn   = w & 3;        // 0..3

    const int raw = blockIdx.x;                // 0..255
    const int kq  = raw >> 3;                  // 0..31
    const int mTile = (kq & 15) * 256;
    const int nTile = (2 * (raw & 7) + (kq >> 4)) * 256;

    const int sRow  = w * 16 + (lane >> 2);                       // 0..127
    const int sColE = ((lane & 3) * 8) ^ ((lane & 32) ? 16 : 0);  // elems in [0,32)
    const bf16* pa0 = A + (size_t)(mTile + sRow) * HIDDEN + sColE;
    const bf16* pa1 = pa0 + (size_t)128 * HIDDEN;
    const int n0 = qk_perm(sRow), n1 = qk_perm(sRow + 128);
    const bf16* pb0 = Bt + (size_t)(nTile + n0) * HIDDEN + sColE;
    const bf16* pb1 = Bt + (size_t)(nTile + n1) * HIDDEN + sColE;

    const int colE = (quad * 8) ^ ((l15 & 8) ? 16 : 0);
    const bf16* lA0 = smem + (wm * 128 + l15) * 32 + colE;
    const bf16* lB0 = smem + 8192 + (wn * 64 + l15) * 32 + colE;

    f32x4 acc[8][4];
#pragma unroll
    for (int i = 0; i < 8; ++i)
#pragma unroll
        for (int j = 0; j < 4; ++j) acc[i][j] = (f32x4){0.f, 0.f, 0.f, 0.f};

#pragma unroll
    for (int tt = 0; tt < 3; ++tt) {
        bf16* dA = smem + tt * 16384 + w * 512;
        async16(pa0 + tt * 32, dA);
        async16(pa1 + tt * 32, dA + 4096);
        async16(pb0 + tt * 32, dA + 8192);
        async16(pb1 + tt * 32, dA + 12288);
    }

#pragma unroll 4
    for (int t = 0; t < 60; ++t) QKV_TILE(t, 1, 8);
    QKV_TILE(60, 1, 8);
    QKV_TILE(61, 0, 8);
    QKV_TILE(62, 0, 4);
    QKV_TILE(63, 0, 0);

    // RoPE epilogue; Q region (cols < 2048) gets the softmax scale folded in.
    const float qs = (nTile < HIDDEN) ? (0.08838834764831845f * 1.4426950408889634f) : 1.0f;
    const int hbase = nTile + (wn >> 1) * 128 + (wn & 1) * 32;
#pragma unroll
    for (int mf = 0; mf < 8; ++mf)
#pragma unroll
        for (int r = 0; r < 4; ++r) {
            int row = mTile + wm * 128 + mf * 16 + quad * 4 + r;
            int s   = row & (SEQ - 1);
            float2 t0 = tab[s * 64 + (wn & 1) * 32 + l15];
            float2 t1 = tab[s * 64 + (wn & 1) * 32 + 16 + l15];
            size_t rb = (size_t)row * QKW + hbase + l15;
            float lo0 = acc[mf][0][r], hi0 = acc[mf][2][r];
            float lo1 = acc[mf][1][r], hi1 = acc[mf][3][r];
            qk[rb]      = (bf16)((lo0 * t0.x - hi0 * t0.y) * qs);
            qk[rb + 64] = (bf16)((hi0 * t0.x + lo0 * t0.y) * qs);
            qk[rb + 16] = (bf16)((lo1 * t1.x - hi1 * t1.y) * qs);
            qk[rb + 80] = (bf16)((hi1 * t1.x + lo1 * t1.y) * qs);
        }
}

// ---------------------------------------------------------------- 128x256 pipeline tile
#define OUT_TILE(T, DOSTAGE, VMN) do {                                          \
    VMW(VMN);                                                                   \
    BARX();                                                                     \
    const bf16* lAr = lA0 + ((T) & 3) * 12288;                                  \
    const bf16* lBr = lB0 + ((T) & 3) * 12288;                                  \
    bf16x8 bfr[4], af[4];                                                       \
    _Pragma("unroll") for (int nf = 0; nf < 4; ++nf)                            \
        bfr[nf] = *(const bf16x8*)(lBr + nf * 512);                             \
    _Pragma("unroll") for (int mf = 0; mf < 4; ++mf)                            \
        af[mf] = *(const bf16x8*)(lAr + mf * 512);                              \
    if (DOSTAGE) {                                                              \
        bf16* dS = smem + (((T) + 3) & 3) * 12288 + w * 512;                    \
        async16(pa0 + ((T) + 3) * 32, dS);                                      \
        async16(pb0 + ((T) + 3) * 32, dS + 4096);                               \
        async16(pb1 + ((T) + 3) * 32, dS + 8192);                               \
    }                                                                           \
    __builtin_amdgcn_s_setprio(1);                                              \
    _Pragma("unroll") for (int mf = 0; mf < 4; ++mf)                            \
    _Pragma("unroll") for (int nf = 0; nf < 4; ++nf)                            \
        acc[mf][nf] = __builtin_amdgcn_mfma_f32_16x16x32_bf16(                  \
            af[mf], bfr[nf], acc[mf][nf], 0, 0, 0);                             \
    __builtin_amdgcn_s_setprio(0);                                              \
} while (0)

#define OUT_PROLOGUE()                                                          \
    const int tid  = threadIdx.x;                                               \
    const int lane = tid & 63;                                                  \
    const int w    = tid >> 6;                                                  \
    const int l15  = lane & 15;                                                 \
    const int quad = lane >> 4;                                                 \
    const int wm   = w >> 2;                                                    \
    const int wn   = w & 3;                                                     \
    const int raw = blockIdx.x;                                                 \
    const int mTile = (raw >> 3) * 128;                                         \
    const int nTile = (raw & 7) * 256;                                          \
    const int sRow  = w * 16 + (lane >> 2);                                     \
    const int sColE = ((lane & 3) * 8) ^ ((lane & 32) ? 16 : 0);                \
    const bf16* pa0 = A + (size_t)(mTile + sRow) * HIDDEN + sColE;              \
    const bf16* pb0 = Bt + (size_t)(nTile + sRow) * HIDDEN + sColE;             \
    const bf16* pb1 = pb0 + (size_t)128 * HIDDEN;                               \
    const int colE = (quad * 8) ^ ((l15 & 8) ? 16 : 0);                         \
    const bf16* lA0 = smem + (wm * 64 + l15) * 32 + colE;                       \
    const bf16* lB0 = smem + 4096 + (wn * 64 + l15) * 32 + colE;                \
    f32x4 acc[4][4];                                                            \
    _Pragma("unroll") for (int i = 0; i < 4; ++i)                               \
    _Pragma("unroll") for (int j = 0; j < 4; ++j)                               \
        acc[i][j] = (f32x4){0.f, 0.f, 0.f, 0.f};                                \
    _Pragma("unroll") for (int tt = 0; tt < 3; ++tt) {                          \
        bf16* dS = smem + tt * 12288 + w * 512;                                 \
        async16(pa0 + tt * 32, dS);                                             \
        async16(pb0 + tt * 32, dS + 4096);                                      \
        async16(pb1 + tt * 32, dS + 8192);                                      \
    }                                                                           \
    _Pragma("unroll 4") for (int t = 0; t < 60; ++t) OUT_TILE(t, 1, 6);         \
    OUT_TILE(60, 1, 6);                                                         \
    OUT_TILE(61, 0, 6);                                                         \
    OUT_TILE(62, 0, 3);                                                         \
    OUT_TILE(63, 0, 0);

// V projection: A[4096 tok][2048] x Wv^T -> vt[feature][token] (transposed bf16 store)
__global__ __launch_bounds__(512, 2) void gemm_v(const bf16* __restrict__ A,
                                                 const bf16* __restrict__ Bt,
                                                 bf16* __restrict__ vtb) {
    __shared__ alignas(16) bf16 smem[49152];   // 96 KiB
    OUT_PROLOGUE()
#pragma unroll
    for (int mf = 0; mf < 4; ++mf)
#pragma unroll
        for (int nf = 0; nf < 4; ++nf) {
            int col_v = nTile + wn * 64 + nf * 16 + l15;        // feature
            int row0  = mTile + wm * 64 + mf * 16 + quad * 4;   // token
            bf16x4 pk;
#pragma unroll
            for (int r = 0; r < 4; ++r) pk[r] = (bf16)acc[mf][nf][r];
            *(bf16x4*)(vtb + (size_t)col_v * BS + row0) = pk;
        }
}

// final proj: out = ao * Wo^T (fp32 row-major store)
__global__ __launch_bounds__(512, 2) void gemm_out(const bf16* __restrict__ A,
                                                   const bf16* __restrict__ Bt,
                                                   float* __restrict__ C) {
    __shared__ alignas(16) bf16 smem[49152];   // 96 KiB
    OUT_PROLOGUE()
#pragma unroll
    for (int mf = 0; mf < 4; ++mf)
#pragma unroll
        for (int nf = 0; nf < 4; ++nf)
#pragma unroll
            for (int r = 0; r < 4; ++r) {
                int row = mTile + wm * 64 + mf * 16 + quad * 4 + r;
                int col = nTile + wn * 64 + nf * 16 + l15;
                C[(size_t)row * HIDDEN + col] = acc[mf][nf][r];
            }
}

// ---------------------------------------------------------------- flash attention (S^T form)
// 4 waves x 32 q-rows (QBLK=128). SINGLE-buffer K/V (32 KB LDS) with interleaved staging:
// stage K(t+1) right after the K-consumed barrier (hides under softmax+PV), stage V(t+1)
// after the V-consumed barrier (hides under next QK). Uniform vmcnt(4) waits. 4 blocks/CU
// co-resident (launch_bounds(256,4), VGPR<=128) -> 16 waves/CU; 512 blocks longest-first
// for dynamic backfill. Q pre-scaled (exp2 domain); raw v_exp_f32; defer-max; setprio.
__global__ __launch_bounds__(256, 4) void attn_kernel(const bf16* __restrict__ qk,
                                                      const bf16* __restrict__ vt,
                                                      bf16* __restrict__ ao) {
    __shared__ bf16 Kls[64 * 128];   // 16 KB: [j][d], 16B chunk c of row j at c^(j&7)
    __shared__ bf16 Vls[128 * 64];   // 16 KB: [d][s], swizzled same

    const int tid  = threadIdx.x;
    const int lane = tid & 63;
    const int w    = tid >> 6;          // 0..3
    const int l15  = lane & 15;
    const int quad = lane >> 4;
    const int bid  = blockIdx.x;
    const int qb2  = 15 - (bid >> 5);   // longest blocks dispatch first
    const int bh   = bid & 31;
    const int b    = bh >> 4;
    const int h    = bh & 15;
    const int qbase = qb2 * 128;
    const int nt    = 2 * qb2 + 2;
    const size_t seq0 = (size_t)b * SEQ;

    // Q fragments: 2 q-subtiles of 16 rows each (pre-scaled by gemm_qk)
    bf16x8 qf[2][4];
#pragma unroll
    for (int qs = 0; qs < 2; ++qs) {
        const bf16* qp = qk + (seq0 + qbase + w * 32 + qs * 16 + l15) * QKW + h * HDIM + quad * 8;
#pragma unroll
        for (int ks = 0; ks < 4; ++ks) qf[qs][ks] = *(const bf16x8*)(qp + ks * 32);
    }
#pragma unroll
    for (int qs = 0; qs < 2; ++qs)
#pragma unroll
        for (int ks = 0; ks < 4; ++ks)
            asm volatile("" :: "v"(*(const f32x4*)&qf[qs][ks]));   // pin Q wait to preheader

    f32x4 o[8][2];
#pragma unroll
    for (int i = 0; i < 8; ++i)
#pragma unroll
        for (int qs = 0; qs < 2; ++qs) o[i][qs] = (f32x4){0.f, 0.f, 0.f, 0.f};
    float m_s[2] = {-3e38f, -3e38f}, l_s[2] = {0.f, 0.f};
    int qg[2];
#pragma unroll
    for (int qs = 0; qs < 2; ++qs) qg[qs] = qbase + w * 32 + qs * 16 + l15;

    const int krow = lane >> 4;
    const int kp   = lane & 15;
    const int vrow = lane >> 3;
    const int vp   = lane & 7;
    const int sw   = l15 & 7;

    // ---- staging sources: uniform SGPR base + 32-bit lane offsets (4 K + 4 V per wave) ----
    const bf16* qksrc = qk + seq0 * QKW + HIDDEN + h * HDIM;          // uniform
    const bf16* vtsrc = vt + (size_t)h * HDIM * BS + seq0;            // uniform
    int koff[4], voff[4];
#pragma unroll
    for (int i = 0; i < 4; ++i) {
        int c = w * 4 + i;                 // 0..15
        int j = c * 4 + krow;              // K row 0..63
        int c2 = (kp & 8) | ((kp & 7) ^ (j & 7));
        koff[i] = j * QKW + c2 * 8;
        int d = c * 8 + vrow;              // V feature row 0..127
        int cv = vp ^ (d & 7);
        voff[i] = d * BS + cv * 8;
    }

    // ---- hoisted LDS read bases; ni/n2 variation -> ds_read immediates ----
    const bf16* kbase[4];
#pragma unroll
    for (int ks = 0; ks < 4; ++ks)
        kbase[ks] = &Kls[l15 * 128 + (((ks * 4 + quad) ^ sw) << 3)];
    const bf16* vbase[4];
#pragma unroll
    for (int ni = 0; ni < 4; ++ni)
        vbase[ni] = &Vls[l15 * 64 + ((((ni * 2 + (quad >> 1)) ^ sw) << 3) + (quad & 1) * 4)];

#define STAGE_K(T) do {                                                          \
        _Pragma("unroll") for (int i = 0; i < 4; ++i)                            \
            async16(qksrc + (size_t)((T) * 64) * QKW + koff[i],                  \
                    &Kls[(w * 4 + i) * 512]);                                    \
    } while (0)
#define STAGE_V(T) do {                                                          \
        _Pragma("unroll") for (int i = 0; i < 4; ++i)                            \
            async16(vtsrc + (T) * 64 + voff[i],                                  \
                    &Vls[(w * 4 + i) * 512]);                                    \
    } while (0)

    STAGE_K(0);
    STAGE_V(0);

    for (int t = 0; t < nt; ++t) {
        VMW(4);                              // own K(t) loads landed (V still in flight)
        BARX();                              // K(t) visible block-wide
        const int kb = t * 64;

        // ---- QK^T ----
        f32x4 sa[4][2];
#pragma unroll
        for (int ni = 0; ni < 4; ++ni)
#pragma unroll
            for (int qs = 0; qs < 2; ++qs) sa[ni][qs] = (f32x4){0.f, 0.f, 0.f, 0.f};
        __builtin_amdgcn_s_setprio(1);
#pragma unroll
        for (int ni = 0; ni < 4; ++ni)
#pragma unroll
            for (int ks = 0; ks < 4; ++ks) {
                bf16x8 kf = *(const bf16x8*)(kbase[ks] + ni * 2048);
                sa[ni][0] = __builtin_amdgcn_mfma_f32_16x16x32_bf16(kf, qf[0][ks], sa[ni][0], 0, 0, 0);
                sa[ni][1] = __builtin_amdgcn_mfma_f32_16x16x32_bf16(kf, qf[1][ks], sa[ni][1], 0, 0, 0);
            }
        __builtin_amdgcn_s_setprio(0);
        BARX();                              // all waves done reading Kls
        if (t + 1 < nt) STAGE_K(t + 1);      // overwrite Kls; lands under softmax+PV

        // ---- softmax (lane-scalar state, defer-max) ----
        const bool diag = (t >= nt - 2);
        b4u pb[4][2];
#pragma unroll
        for (int qs = 0; qs < 2; ++qs) {
            float rmax = -3e38f;
#pragma unroll
            for (int ni = 0; ni < 4; ++ni)
#pragma unroll
                for (int r = 0; r < 4; ++r) {
                    float sv = sa[ni][qs][r];
                    if (diag && (kb + ni * 16 + quad * 4 + r > qg[qs])) sv = -1e30f;
                    sa[ni][qs][r] = sv;
                    rmax = fmaxf(rmax, sv);
                }
            rmax = fmaxf(rmax, __shfl_xor(rmax, 16));
            rmax = fmaxf(rmax, __shfl_xor(rmax, 32));
            if (__ballot(rmax > m_s[qs] + 8.f) != 0ull) {
                float mn = fmaxf(m_s[qs], rmax);
                float al = ex2(m_s[qs] - mn);
                m_s[qs] = mn; l_s[qs] *= al;
#pragma unroll
                for (int n2 = 0; n2 < 8; ++n2)
#pragma unroll
                    for (int r = 0; r < 4; ++r) o[n2][qs][r] *= al;
            }
            float rsum = 0.f;
#pragma unroll
            for (int ni = 0; ni < 4; ++ni)
#pragma unroll
                for (int r = 0; r < 4; ++r) {
                    float e = ex2(sa[ni][qs][r] - m_s[qs]);
                    rsum += e;
                    pb[ni][qs].h[r] = (bf16)e;
                }
            rsum += __shfl_xor(rsum, 16);
            rsum += __shfl_xor(rsum, 32);
            l_s[qs] += rsum;
        }

        if (t + 1 < nt) { VMW(4); }          // own V(t) landed (K(t+1) in flight)
        else            { VMW(0); }
        BARX();                              // V(t) visible block-wide

        // ---- PV ----
        __builtin_amdgcn_s_setprio(1);
#pragma unroll
        for (int n2 = 0; n2 < 8; ++n2)
#pragma unroll
            for (int ni = 0; ni < 4; ++ni) {
                b4u vf;
                vf.h = *(const bf16x4*)(vbase[ni] + n2 * 1024);
                o[n2][0] = __builtin_amdgcn_mfma_f32_16x16x16bf16_1k(vf.s, pb[ni][0].s, o[n2][0], 0, 0, 0);
                o[n2][1] = __builtin_amdgcn_mfma_f32_16x16x16bf16_1k(vf.s, pb[ni][1].s, o[n2][1], 0, 0, 0);
            }
        __builtin_amdgcn_s_setprio(0);
        BARX();                              // all waves done reading Vls
        if (t + 1 < nt) STAGE_V(t + 1);      // overwrite Vls; lands under next QK
    }
#undef STAGE_K
#undef STAGE_V

#pragma unroll
    for (int qs = 0; qs < 2; ++qs) {
        const float inv = 1.0f / l_s[qs];
        bf16* op = ao + (seq0 + qg[qs]) * HIDDEN + h * HDIM + quad * 4;
#pragma unroll
        for (int n2 = 0; n2 < 8; ++n2) {
            bf16x4 pk;
#pragma unroll
            for (int r = 0; r < 4; ++r) pk[r] = (bf16)(o[n2][qs][r] * inv);
            *(bf16x4*)(op + n2 * 16) = pk;
        }
    }
}

// ---------------------------------------------------------------- launch
extern "C" void kernel_launch(void* const* d_in, const int* in_sizes, int n_in,
                              void* d_out, int out_size, void* d_ws, size_t ws_size,
                              hipStream_t stream) {
    const float* hs = (const float*)d_in[0];
    const float* Wq = (const float*)d_in[1];
    const float* Wk = (const float*)d_in[2];
    const float* Wv = (const float*)d_in[3];
    const float* Wo = (const float*)d_in[4];
    const int* pos  = (const int*)d_in[6];
    float* out = (float*)d_out;

    bf16* hs_b = (bf16*)d_ws;                               //  8,388,608 el
    bf16* wqkv = hs_b + (size_t)8388608;                    // 12,582,912 el [6144][2048]
    bf16* wo_b = wqkv + (size_t)12582912;                   //  4,194,304 el
    bf16* qkb  = wo_b + (size_t)4194304;                    // 16,777,216 el [4096][4096]
    bf16* vtb  = qkb + (size_t)16777216;                    //  8,388,608 el [2048][4096]
    bf16* ao   = vtb + (size_t)8388608;                     //  8,388,608 el
    float2* tab = (float2*)ao;  // 1 MB, consumed by gemm_qk BEFORE attn writes ao

    cast_all<<<25088, 256, 0, stream>>>(hs, Wq, Wk, Wv, Wo, pos, hs_b, wqkv, wo_b, tab);
    gemm_qk<<<256, 512, 0, stream>>>(hs_b, wqkv, tab, qkb);
    gemm_v<<<256, 512, 0, stream>>>(hs_b, wqkv + (size_t)8388608, vtb);
    attn_kernel<<<512, 256, 0, stream>>>(qkb, vtb, ao);
    gemm_out<<<256, 512, 0, stream>>>(ao, wo_b, out);
}

// Round 7
// 386.086 us; speedup vs baseline: 1.3407x; 1.3407x over previous
//
#include <hip/hip_runtime.h>
#include <cstdint>
#include <cstddef>

typedef __bf16 bf16;
typedef __bf16 bf16x4 __attribute__((ext_vector_type(4)));
typedef __bf16 bf16x8 __attribute__((ext_vector_type(8)));
typedef float  f32x4  __attribute__((ext_vector_type(4)));
typedef short  s16x4  __attribute__((ext_vector_type(4)));

#define HIDDEN 2048
#define NHEADS 16
#define HDIM   128
#define BSZ    2
#define SEQ    2048
#define BS     (BSZ*SEQ)     /* 4096 rows */
#define QKW    (2*HIDDEN)    /* 4096: Q|K concat width */

union b4u { bf16x4 h; s16x4 s; };

// async global->LDS, 16B per lane. LDS dest = wave-uniform base + lane*16.
__device__ __forceinline__ void async16(const bf16* g, bf16* l) {
    __builtin_amdgcn_global_load_lds(
        (const __attribute__((address_space(1))) unsigned int*)g,
        (__attribute__((address_space(3))) unsigned int*)l, 16, 0, 0);
}

#define BARX()  asm volatile("s_barrier" ::: "memory")
#define VMW(N)  asm volatile("s_waitcnt vmcnt(" #N ")" ::: "memory")

// raw v_exp_f32: exp2 is the native op, skip OCML fixups (args are <= 8, large-neg -> 0)
__device__ __forceinline__ float ex2(float x) {
    float r; asm("v_exp_f32 %0, %1" : "=v"(r) : "v"(x)); return r;
}

// ---------------------------------------------------------------- fused casts + rope table
__global__ __launch_bounds__(256) void cast_all(const float* __restrict__ hs,
                                                const float* __restrict__ Wq,
                                                const float* __restrict__ Wk,
                                                const float* __restrict__ Wv,
                                                const float* __restrict__ Wo,
                                                const int* __restrict__ pos,
                                                bf16* __restrict__ hs_b,
                                                bf16* __restrict__ wqkv,
                                                bf16* __restrict__ wo_b,
                                                float2* __restrict__ tab) {
    int i = blockIdx.x * 256 + threadIdx.x;
    if (i >= 6291456) {                       // rope table region
        int j = i - 6291456;                  // 0..131071
        int s = j >> 6, p = j & 63;
        float t = (float)pos[s];
        float inv = expf(-(float)(2 * p) * (9.2103403719761836f / 128.0f));
        float sn, cs;
        sincosf(t * inv, &sn, &cs);
        tab[j] = make_float2(cs, sn);
        return;
    }
    const float* src; bf16* dst; int off;
    if (i < 2097152) { src = hs; dst = hs_b; off = i; }
    else {
        int j = i - 2097152;
        int r = j >> 20;
        off = j & 1048575;
        if      (r == 0) { src = Wq; dst = wqkv; }
        else if (r == 1) { src = Wk; dst = wqkv + (size_t)4194304; }
        else if (r == 2) { src = Wv; dst = wqkv + (size_t)8388608; }
        else             { src = Wo; dst = wo_b; }
    }
    const float4 v = ((const float4*)src)[off];
    bf16x4 o;
    o.x = (bf16)v.x; o.y = (bf16)v.y; o.z = (bf16)v.z; o.w = (bf16)v.w;
    ((bf16x4*)dst)[off] = o;
}

// ---------------------------------------------------------------- Q|K GEMM + RoPE
// 256x256 tile, BK=32, 512 thr (8 waves 2M x 4N), ring-4 LDS, counted vmcnt,
// st_16x32 swizzle, setprio. Grid 256 = EXACTLY one full round on 256 CUs.
// Q region written PRE-SCALED by 1/sqrt(128)*log2(e) so attn's S is exp2-domain.
__device__ __forceinline__ int qk_perm(int n) {
    int wl = n >> 6, j = n & 63;
    return ((wl >> 1) << 7) | ((j >> 5) << 6) | ((wl & 1) << 5) | (j & 31);
}

#define QKV_TILE(T, DOSTAGE, VMN) do {                                          \
    VMW(VMN);                                                                   \
    BARX();                                                                     \
    const bf16* lAr = lA0 + ((T) & 3) * 16384;                                  \
    const bf16* lBr = lB0 + ((T) & 3) * 16384;                                  \
    bf16x8 bfr[4], af[4];                                                       \
    _Pragma("unroll") for (int nf = 0; nf < 4; ++nf)                            \
        bfr[nf] = *(const bf16x8*)(lBr + nf * 512);                             \
    _Pragma("unroll") for (int mf = 0; mf < 4; ++mf)                            \
        af[mf] = *(const bf16x8*)(lAr + mf * 512);                              \
    if (DOSTAGE) {                                                              \
        bf16* dA = smem + (((T) + 3) & 3) * 16384 + w * 512;                    \
        async16(pa0 + ((T) + 3) * 32, dA);                                      \
        async16(pa1 + ((T) + 3) * 32, dA + 4096);                               \
    }                                                                           \
    __builtin_amdgcn_s_setprio(1);                                              \
    _Pragma("unroll") for (int mf = 0; mf < 4; ++mf)                            \
    _Pragma("unroll") for (int nf = 0; nf < 4; ++nf)                            \
        acc[mf][nf] = __builtin_amdgcn_mfma_f32_16x16x32_bf16(                  \
            af[mf], bfr[nf], acc[mf][nf], 0, 0, 0);                             \
    __builtin_amdgcn_s_setprio(0);                                              \
    _Pragma("unroll") for (int mf = 0; mf < 4; ++mf)                            \
        af[mf] = *(const bf16x8*)(lAr + 2048 + mf * 512);                       \
    if (DOSTAGE) {                                                              \
        bf16* dB = smem + (((T) + 3) & 3) * 16384 + 8192 + w * 512;             \
        async16(pb0 + ((T) + 3) * 32, dB);                                      \
        async16(pb1 + ((T) + 3) * 32, dB + 4096);                               \
    }                                                                           \
    __builtin_amdgcn_s_setprio(1);                                              \
    _Pragma("unroll") for (int mf = 0; mf < 4; ++mf)                            \
    _Pragma("unroll") for (int nf = 0; nf < 4; ++nf)                            \
        acc[4 + mf][nf] = __builtin_amdgcn_mfma_f32_16x16x32_bf16(              \
            af[mf], bfr[nf], acc[4 + mf][nf], 0, 0, 0);                         \
    __builtin_amdgcn_s_setprio(0);                                              \
} while (0)

__global__ __launch_bounds__(512, 2) void gemm_qk(const bf16* __restrict__ A,
                                                  const bf16* __restrict__ Bt,
                                                  const float2* __restrict__ tab,
                                                  bf16* __restrict__ qk) {
    __shared__ alignas(16) bf16 smem[65536];   // 128 KiB: 4 bufs x (A 8192 | B 8192)

    const int tid  = threadIdx.x;
    const int lane = tid & 63;
    const int w    = tid >> 6;
    const int l15  = lane & 15;
    const int quad = lane >> 4;
    const int wm   = w >> 2;       // 0..1
    const int wn   = w & 3;        // 0..3

    const int raw = blockIdx.x;                // 0..255
    const int kq  = raw >> 3;                  // 0..31
    const int mTile = (kq & 15) * 256;
    const int nTile = (2 * (raw & 7) + (kq >> 4)) * 256;

    const int sRow  = w * 16 + (lane >> 2);                       // 0..127
    const int sColE = ((lane & 3) * 8) ^ ((lane & 32) ? 16 : 0);  // elems in [0,32)
    const bf16* pa0 = A + (size_t)(mTile + sRow) * HIDDEN + sColE;
    const bf16* pa1 = pa0 + (size_t)128 * HIDDEN;
    const int n0 = qk_perm(sRow), n1 = qk_perm(sRow + 128);
    const bf16* pb0 = Bt + (size_t)(nTile + n0) * HIDDEN + sColE;
    const bf16* pb1 = Bt + (size_t)(nTile + n1) * HIDDEN + sColE;

    const int colE = (quad * 8) ^ ((l15 & 8) ? 16 : 0);
    const bf16* lA0 = smem + (wm * 128 + l15) * 32 + colE;
    const bf16* lB0 = smem + 8192 + (wn * 64 + l15) * 32 + colE;

    f32x4 acc[8][4];
#pragma unroll
    for (int i = 0; i < 8; ++i)
#pragma unroll
        for (int j = 0; j < 4; ++j) acc[i][j] = (f32x4){0.f, 0.f, 0.f, 0.f};

#pragma unroll
    for (int tt = 0; tt < 3; ++tt) {
        bf16* dA = smem + tt * 16384 + w * 512;
        async16(pa0 + tt * 32, dA);
        async16(pa1 + tt * 32, dA + 4096);
        async16(pb0 + tt * 32, dA + 8192);
        async16(pb1 + tt * 32, dA + 12288);
    }

#pragma unroll 4
    for (int t = 0; t < 60; ++t) QKV_TILE(t, 1, 8);
    QKV_TILE(60, 1, 8);
    QKV_TILE(61, 0, 8);
    QKV_TILE(62, 0, 4);
    QKV_TILE(63, 0, 0);

    // RoPE epilogue; Q region (cols < 2048) gets the softmax scale folded in.
    const float qs = (nTile < HIDDEN) ? (0.08838834764831845f * 1.4426950408889634f) : 1.0f;
    const int hbase = nTile + (wn >> 1) * 128 + (wn & 1) * 32;
#pragma unroll
    for (int mf = 0; mf < 8; ++mf)
#pragma unroll
        for (int r = 0; r < 4; ++r) {
            int row = mTile + wm * 128 + mf * 16 + quad * 4 + r;
            int s   = row & (SEQ - 1);
            float2 t0 = tab[s * 64 + (wn & 1) * 32 + l15];
            float2 t1 = tab[s * 64 + (wn & 1) * 32 + 16 + l15];
            size_t rb = (size_t)row * QKW + hbase + l15;
            float lo0 = acc[mf][0][r], hi0 = acc[mf][2][r];
            float lo1 = acc[mf][1][r], hi1 = acc[mf][3][r];
            qk[rb]      = (bf16)((lo0 * t0.x - hi0 * t0.y) * qs);
            qk[rb + 64] = (bf16)((hi0 * t0.x + lo0 * t0.y) * qs);
            qk[rb + 16] = (bf16)((lo1 * t1.x - hi1 * t1.y) * qs);
            qk[rb + 80] = (bf16)((hi1 * t1.x + lo1 * t1.y) * qs);
        }
}

// ---------------------------------------------------------------- 128x256 pipeline tile
#define OUT_TILE(T, DOSTAGE, VMN) do {                                          \
    VMW(VMN);                                                                   \
    BARX();                                                                     \
    const bf16* lAr = lA0 + ((T) & 3) * 12288;                                  \
    const bf16* lBr = lB0 + ((T) & 3) * 12288;                                  \
    bf16x8 bfr[4], af[4];                                                       \
    _Pragma("unroll") for (int nf = 0; nf < 4; ++nf)                            \
        bfr[nf] = *(const bf16x8*)(lBr + nf * 512);                             \
    _Pragma("unroll") for (int mf = 0; mf < 4; ++mf)                            \
        af[mf] = *(const bf16x8*)(lAr + mf * 512);                              \
    if (DOSTAGE) {                                                              \
        bf16* dS = smem + (((T) + 3) & 3) * 12288 + w * 512;                    \
        async16(pa0 + ((T) + 3) * 32, dS);                                      \
        async16(pb0 + ((T) + 3) * 32, dS + 4096);                               \
        async16(pb1 + ((T) + 3) * 32, dS + 8192);                               \
    }                                                                           \
    __builtin_amdgcn_s_setprio(1);                                              \
    _Pragma("unroll") for (int mf = 0; mf < 4; ++mf)                            \
    _Pragma("unroll") for (int nf = 0; nf < 4; ++nf)                            \
        acc[mf][nf] = __builtin_amdgcn_mfma_f32_16x16x32_bf16(                  \
            af[mf], bfr[nf], acc[mf][nf], 0, 0, 0);                             \
    __builtin_amdgcn_s_setprio(0);                                              \
} while (0)

#define OUT_PROLOGUE()                                                          \
    const int tid  = threadIdx.x;                                               \
    const int lane = tid & 63;                                                  \
    const int w    = tid >> 6;                                                  \
    const int l15  = lane & 15;                                                 \
    const int quad = lane >> 4;                                                 \
    const int wm   = w >> 2;                                                    \
    const int wn   = w & 3;                                                     \
    const int raw = blockIdx.x;                                                 \
    const int mTile = (raw >> 3) * 128;                                         \
    const int nTile = (raw & 7) * 256;                                          \
    const int sRow  = w * 16 + (lane >> 2);                                     \
    const int sColE = ((lane & 3) * 8) ^ ((lane & 32) ? 16 : 0);                \
    const bf16* pa0 = A + (size_t)(mTile + sRow) * HIDDEN + sColE;              \
    const bf16* pb0 = Bt + (size_t)(nTile + sRow) * HIDDEN + sColE;             \
    const bf16* pb1 = pb0 + (size_t)128 * HIDDEN;                               \
    const int colE = (quad * 8) ^ ((l15 & 8) ? 16 : 0);                         \
    const bf16* lA0 = smem + (wm * 64 + l15) * 32 + colE;                       \
    const bf16* lB0 = smem + 4096 + (wn * 64 + l15) * 32 + colE;                \
    f32x4 acc[4][4];                                                            \
    _Pragma("unroll") for (int i = 0; i < 4; ++i)                               \
    _Pragma("unroll") for (int j = 0; j < 4; ++j)                               \
        acc[i][j] = (f32x4){0.f, 0.f, 0.f, 0.f};                                \
    _Pragma("unroll") for (int tt = 0; tt < 3; ++tt) {                          \
        bf16* dS = smem + tt * 12288 + w * 512;                                 \
        async16(pa0 + tt * 32, dS);                                             \
        async16(pb0 + tt * 32, dS + 4096);                                      \
        async16(pb1 + tt * 32, dS + 8192);                                      \
    }                                                                           \
    _Pragma("unroll 4") for (int t = 0; t < 60; ++t) OUT_TILE(t, 1, 6);         \
    OUT_TILE(60, 1, 6);                                                         \
    OUT_TILE(61, 0, 6);                                                         \
    OUT_TILE(62, 0, 3);                                                         \
    OUT_TILE(63, 0, 0);

// V projection: A[4096 tok][2048] x Wv^T -> vt[feature][token] (transposed bf16 store)
__global__ __launch_bounds__(512, 2) void gemm_v(const bf16* __restrict__ A,
                                                 const bf16* __restrict__ Bt,
                                                 bf16* __restrict__ vtb) {
    __shared__ alignas(16) bf16 smem[49152];   // 96 KiB
    OUT_PROLOGUE()
#pragma unroll
    for (int mf = 0; mf < 4; ++mf)
#pragma unroll
        for (int nf = 0; nf < 4; ++nf) {
            int col_v = nTile + wn * 64 + nf * 16 + l15;        // feature
            int row0  = mTile + wm * 64 + mf * 16 + quad * 4;   // token
            bf16x4 pk;
#pragma unroll
            for (int r = 0; r < 4; ++r) pk[r] = (bf16)acc[mf][nf][r];
            *(bf16x4*)(vtb + (size_t)col_v * BS + row0) = pk;
        }
}

// final proj: out = ao * Wo^T (fp32 row-major store)
__global__ __launch_bounds__(512, 2) void gemm_out(const bf16* __restrict__ A,
                                                   const bf16* __restrict__ Bt,
                                                   float* __restrict__ C) {
    __shared__ alignas(16) bf16 smem[49152];   // 96 KiB
    OUT_PROLOGUE()
#pragma unroll
    for (int mf = 0; mf < 4; ++mf)
#pragma unroll
        for (int nf = 0; nf < 4; ++nf)
#pragma unroll
            for (int r = 0; r < 4; ++r) {
                int row = mTile + wm * 64 + mf * 16 + quad * 4 + r;
                int col = nTile + wn * 64 + nf * 16 + l15;
                C[(size_t)row * HIDDEN + col] = acc[mf][nf][r];
            }
}

// ---------------------------------------------------------------- flash attention (S^T form)
// 4 waves x 32 q-rows (QBLK=128). SINGLE-buffer K/V (32 KB LDS) with interleaved staging:
// stage K(t+1) right after the K-consumed barrier (hides under softmax+PV), stage V(t+1)
// after the V-consumed barrier (hides under next QK). Uniform vmcnt(4) waits.
// launch_bounds(256,2): cap 256 VGPRs -> compiler lands ~112, occupancy comes from ACTUAL
// usage (112 VGPR -> 16 waves/CU; 32KB LDS -> 5 blocks/CU) — NOT from forcing the bound
// (R6's (256,4) capped at 64 VGPR and spilled ~300MB to scratch). 512 blocks longest-first.
__global__ __launch_bounds__(256, 2) void attn_kernel(const bf16* __restrict__ qk,
                                                      const bf16* __restrict__ vt,
                                                      bf16* __restrict__ ao) {
    __shared__ bf16 Kls[64 * 128];   // 16 KB: [j][d], 16B chunk c of row j at c^(j&7)
    __shared__ bf16 Vls[128 * 64];   // 16 KB: [d][s], swizzled same

    const int tid  = threadIdx.x;
    const int lane = tid & 63;
    const int w    = tid >> 6;          // 0..3
    const int l15  = lane & 15;
    const int quad = lane >> 4;
    const int bid  = blockIdx.x;
    const int qb2  = 15 - (bid >> 5);   // longest blocks dispatch first
    const int bh   = bid & 31;
    const int b    = bh >> 4;
    const int h    = bh & 15;
    const int qbase = qb2 * 128;
    const int nt    = 2 * qb2 + 2;
    const size_t seq0 = (size_t)b * SEQ;

    // Q fragments: 2 q-subtiles of 16 rows each (pre-scaled by gemm_qk)
    bf16x8 qf[2][4];
#pragma unroll
    for (int qs = 0; qs < 2; ++qs) {
        const bf16* qp = qk + (seq0 + qbase + w * 32 + qs * 16 + l15) * QKW + h * HDIM + quad * 8;
#pragma unroll
        for (int ks = 0; ks < 4; ++ks) qf[qs][ks] = *(const bf16x8*)(qp + ks * 32);
    }
#pragma unroll
    for (int qs = 0; qs < 2; ++qs)
#pragma unroll
        for (int ks = 0; ks < 4; ++ks)
            asm volatile("" :: "v"(*(const f32x4*)&qf[qs][ks]));   // pin Q wait to preheader

    f32x4 o[8][2];
#pragma unroll
    for (int i = 0; i < 8; ++i)
#pragma unroll
        for (int qs = 0; qs < 2; ++qs) o[i][qs] = (f32x4){0.f, 0.f, 0.f, 0.f};
    float m_s[2] = {-3e38f, -3e38f}, l_s[2] = {0.f, 0.f};
    int qg[2];
#pragma unroll
    for (int qs = 0; qs < 2; ++qs) qg[qs] = qbase + w * 32 + qs * 16 + l15;

    const int krow = lane >> 4;
    const int kp   = lane & 15;
    const int vrow = lane >> 3;
    const int vp   = lane & 7;
    const int sw   = l15 & 7;

    // ---- staging sources: uniform SGPR base + 32-bit lane offsets (4 K + 4 V per wave) ----
    const bf16* qksrc = qk + seq0 * QKW + HIDDEN + h * HDIM;          // uniform
    const bf16* vtsrc = vt + (size_t)h * HDIM * BS + seq0;            // uniform
    int koff[4], voff[4];
#pragma unroll
    for (int i = 0; i < 4; ++i) {
        int c = w * 4 + i;                 // 0..15
        int j = c * 4 + krow;              // K row 0..63
        int c2 = (kp & 8) | ((kp & 7) ^ (j & 7));
        koff[i] = j * QKW + c2 * 8;
        int d = c * 8 + vrow;              // V feature row 0..127
        int cv = vp ^ (d & 7);
        voff[i] = d * BS + cv * 8;
    }

    // ---- hoisted LDS read bases; ni/n2 variation -> ds_read immediates ----
    const bf16* kbase[4];
#pragma unroll
    for (int ks = 0; ks < 4; ++ks)
        kbase[ks] = &Kls[l15 * 128 + (((ks * 4 + quad) ^ sw) << 3)];
    const bf16* vbase[4];
#pragma unroll
    for (int ni = 0; ni < 4; ++ni)
        vbase[ni] = &Vls[l15 * 64 + ((((ni * 2 + (quad >> 1)) ^ sw) << 3) + (quad & 1) * 4)];

#define STAGE_K(T) do {                                                          \
        _Pragma("unroll") for (int i = 0; i < 4; ++i)                            \
            async16(qksrc + (size_t)((T) * 64) * QKW + koff[i],                  \
                    &Kls[(w * 4 + i) * 512]);                                    \
    } while (0)
#define STAGE_V(T) do {                                                          \
        _Pragma("unroll") for (int i = 0; i < 4; ++i)                            \
            async16(vtsrc + (T) * 64 + voff[i],                                  \
                    &Vls[(w * 4 + i) * 512]);                                    \
    } while (0)

    STAGE_K(0);
    STAGE_V(0);

    for (int t = 0; t < nt; ++t) {
        VMW(4);                              // own K(t) loads landed (V still in flight)
        BARX();                              // K(t) visible block-wide
        const int kb = t * 64;

        // ---- QK^T ----
        f32x4 sa[4][2];
#pragma unroll
        for (int ni = 0; ni < 4; ++ni)
#pragma unroll
            for (int qs = 0; qs < 2; ++qs) sa[ni][qs] = (f32x4){0.f, 0.f, 0.f, 0.f};
        __builtin_amdgcn_s_setprio(1);
#pragma unroll
        for (int ni = 0; ni < 4; ++ni)
#pragma unroll
            for (int ks = 0; ks < 4; ++ks) {
                bf16x8 kf = *(const bf16x8*)(kbase[ks] + ni * 2048);
                sa[ni][0] = __builtin_amdgcn_mfma_f32_16x16x32_bf16(kf, qf[0][ks], sa[ni][0], 0, 0, 0);
                sa[ni][1] = __builtin_amdgcn_mfma_f32_16x16x32_bf16(kf, qf[1][ks], sa[ni][1], 0, 0, 0);
            }
        __builtin_amdgcn_s_setprio(0);
        BARX();                              // all waves done reading Kls
        if (t + 1 < nt) STAGE_K(t + 1);      // overwrite Kls; lands under softmax+PV

        // ---- softmax (lane-scalar state, defer-max) ----
        const bool diag = (t >= nt - 2);
        b4u pb[4][2];
#pragma unroll
        for (int qs = 0; qs < 2; ++qs) {
            float rmax = -3e38f;
#pragma unroll
            for (int ni = 0; ni < 4; ++ni)
#pragma unroll
                for (int r = 0; r < 4; ++r) {
                    float sv = sa[ni][qs][r];
                    if (diag && (kb + ni * 16 + quad * 4 + r > qg[qs])) sv = -1e30f;
                    sa[ni][qs][r] = sv;
                    rmax = fmaxf(rmax, sv);
                }
            rmax = fmaxf(rmax, __shfl_xor(rmax, 16));
            rmax = fmaxf(rmax, __shfl_xor(rmax, 32));
            if (__ballot(rmax > m_s[qs] + 8.f) != 0ull) {
                float mn = fmaxf(m_s[qs], rmax);
                float al = ex2(m_s[qs] - mn);
                m_s[qs] = mn; l_s[qs] *= al;
#pragma unroll
                for (int n2 = 0; n2 < 8; ++n2)
#pragma unroll
                    for (int r = 0; r < 4; ++r) o[n2][qs][r] *= al;
            }
            float rsum = 0.f;
#pragma unroll
            for (int ni = 0; ni < 4; ++ni)
#pragma unroll
                for (int r = 0; r < 4; ++r) {
                    float e = ex2(sa[ni][qs][r] - m_s[qs]);
                    rsum += e;
                    pb[ni][qs].h[r] = (bf16)e;
                }
            rsum += __shfl_xor(rsum, 16);
            rsum += __shfl_xor(rsum, 32);
            l_s[qs] += rsum;
        }

        if (t + 1 < nt) { VMW(4); }          // own V(t) landed (K(t+1) in flight)
        else            { VMW(0); }
        BARX();                              // V(t) visible block-wide

        // ---- PV ----
        __builtin_amdgcn_s_setprio(1);
#pragma unroll
        for (int n2 = 0; n2 < 8; ++n2)
#pragma unroll
            for (int ni = 0; ni < 4; ++ni) {
                b4u vf;
                vf.h = *(const bf16x4*)(vbase[ni] + n2 * 1024);
                o[n2][0] = __builtin_amdgcn_mfma_f32_16x16x16bf16_1k(vf.s, pb[ni][0].s, o[n2][0], 0, 0, 0);
                o[n2][1] = __builtin_amdgcn_mfma_f32_16x16x16bf16_1k(vf.s, pb[ni][1].s, o[n2][1], 0, 0, 0);
            }
        __builtin_amdgcn_s_setprio(0);
        BARX();                              // all waves done reading Vls
        if (t + 1 < nt) STAGE_V(t + 1);      // overwrite Vls; lands under next QK
    }
#undef STAGE_K
#undef STAGE_V

#pragma unroll
    for (int qs = 0; qs < 2; ++qs) {
        const float inv = 1.0f / l_s[qs];
        bf16* op = ao + (seq0 + qg[qs]) * HIDDEN + h * HDIM + quad * 4;
#pragma unroll
        for (int n2 = 0; n2 < 8; ++n2) {
            bf16x4 pk;
#pragma unroll
            for (int r = 0; r < 4; ++r) pk[r] = (bf16)(o[n2][qs][r] * inv);
            *(bf16x4*)(op + n2 * 16) = pk;
        }
    }
}

// ---------------------------------------------------------------- launch
extern "C" void kernel_launch(void* const* d_in, const int* in_sizes, int n_in,
                              void* d_out, int out_size, void* d_ws, size_t ws_size,
                              hipStream_t stream) {
    const float* hs = (const float*)d_in[0];
    const float* Wq = (const float*)d_in[1];
    const float* Wk = (const float*)d_in[2];
    const float* Wv = (const float*)d_in[3];
    const float* Wo = (const float*)d_in[4];
    const int* pos  = (const int*)d_in[6];
    float* out = (float*)d_out;

    bf16* hs_b = (bf16*)d_ws;                               //  8,388,608 el
    bf16* wqkv = hs_b + (size_t)8388608;                    // 12,582,912 el [6144][2048]
    bf16* wo_b = wqkv + (size_t)12582912;                   //  4,194,304 el
    bf16* qkb  = wo_b + (size_t)4194304;                    // 16,777,216 el [4096][4096]
    bf16* vtb  = qkb + (size_t)16777216;                    //  8,388,608 el [2048][4096]
    bf16* ao   = vtb + (size_t)8388608;                     //  8,388,608 el
    float2* tab = (float2*)ao;  // 1 MB, consumed by gemm_qk BEFORE attn writes ao

    cast_all<<<25088, 256, 0, stream>>>(hs, Wq, Wk, Wv, Wo, pos, hs_b, wqkv, wo_b, tab);
    gemm_qk<<<256, 512, 0, stream>>>(hs_b, wqkv, tab, qkb);
    gemm_v<<<256, 512, 0, stream>>>(hs_b, wqkv + (size_t)8388608, vtb);
    attn_kernel<<<512, 256, 0, stream>>>(qkb, vtb, ao);
    gemm_out<<<256, 512, 0, stream>>>(ao, wo_b, out);
}

// Round 8
// 385.727 us; speedup vs baseline: 1.3420x; 1.0009x over previous
//
#include <hip/hip_runtime.h>
#include <cstdint>
#include <cstddef>

typedef __bf16 bf16;
typedef __bf16 bf16x4 __attribute__((ext_vector_type(4)));
typedef __bf16 bf16x8 __attribute__((ext_vector_type(8)));
typedef float  f32x4  __attribute__((ext_vector_type(4)));
typedef short  s16x4  __attribute__((ext_vector_type(4)));

#define HIDDEN 2048
#define NHEADS 16
#define HDIM   128
#define BSZ    2
#define SEQ    2048
#define BS     (BSZ*SEQ)     /* 4096 rows */
#define QKW    (2*HIDDEN)    /* 4096: Q|K concat width */

union b4u { bf16x4 h; s16x4 s; };

// async global->LDS, 16B per lane. LDS dest = wave-uniform base + lane*16.
__device__ __forceinline__ void async16(const bf16* g, bf16* l) {
    __builtin_amdgcn_global_load_lds(
        (const __attribute__((address_space(1))) unsigned int*)g,
        (__attribute__((address_space(3))) unsigned int*)l, 16, 0, 0);
}

#define BARX()  asm volatile("s_barrier" ::: "memory")
#define VMW(N)  asm volatile("s_waitcnt vmcnt(" #N ")" ::: "memory")

// raw v_exp_f32: exp2 is the native op, skip OCML fixups (args are <= 8, large-neg -> 0)
__device__ __forceinline__ float ex2(float x) {
    float r; asm("v_exp_f32 %0, %1" : "=v"(r) : "v"(x)); return r;
}

// ---------------------------------------------------------------- fused casts + rope table
__global__ __launch_bounds__(256) void cast_all(const float* __restrict__ hs,
                                                const float* __restrict__ Wq,
                                                const float* __restrict__ Wk,
                                                const float* __restrict__ Wv,
                                                const float* __restrict__ Wo,
                                                const int* __restrict__ pos,
                                                bf16* __restrict__ hs_b,
                                                bf16* __restrict__ wqkv,
                                                bf16* __restrict__ wo_b,
                                                float2* __restrict__ tab) {
    int i = blockIdx.x * 256 + threadIdx.x;
    if (i >= 6291456) {                       // rope table region
        int j = i - 6291456;                  // 0..131071
        int s = j >> 6, p = j & 63;
        float t = (float)pos[s];
        float inv = expf(-(float)(2 * p) * (9.2103403719761836f / 128.0f));
        float sn, cs;
        sincosf(t * inv, &sn, &cs);
        tab[j] = make_float2(cs, sn);
        return;
    }
    const float* src; bf16* dst; int off;
    if (i < 2097152) { src = hs; dst = hs_b; off = i; }
    else {
        int j = i - 2097152;
        int r = j >> 20;
        off = j & 1048575;
        if      (r == 0) { src = Wq; dst = wqkv; }
        else if (r == 1) { src = Wk; dst = wqkv + (size_t)4194304; }
        else if (r == 2) { src = Wv; dst = wqkv + (size_t)8388608; }
        else             { src = Wo; dst = wo_b; }
    }
    const float4 v = ((const float4*)src)[off];
    bf16x4 o;
    o.x = (bf16)v.x; o.y = (bf16)v.y; o.z = (bf16)v.z; o.w = (bf16)v.w;
    ((bf16x4*)dst)[off] = o;
}

// ---------------------------------------------------------------- Q|K GEMM + RoPE
__device__ __forceinline__ int qk_perm(int n) {
    int wl = n >> 6, j = n & 63;
    return ((wl >> 1) << 7) | ((j >> 5) << 6) | ((wl & 1) << 5) | (j & 31);
}

#define QKV_TILE(T, DOSTAGE, VMN) do {                                          \
    VMW(VMN);                                                                   \
    BARX();                                                                     \
    const bf16* lAr = lA0 + ((T) & 3) * 16384;                                  \
    const bf16* lBr = lB0 + ((T) & 3) * 16384;                                  \
    bf16x8 bfr[4], af[4];                                                       \
    _Pragma("unroll") for (int nf = 0; nf < 4; ++nf)                            \
        bfr[nf] = *(const bf16x8*)(lBr + nf * 512);                             \
    _Pragma("unroll") for (int mf = 0; mf < 4; ++mf)                            \
        af[mf] = *(const bf16x8*)(lAr + mf * 512);                              \
    if (DOSTAGE) {                                                              \
        bf16* dA = smem + (((T) + 3) & 3) * 16384 + w * 512;                    \
        async16(pa0 + ((T) + 3) * 32, dA);                                      \
        async16(pa1 + ((T) + 3) * 32, dA + 4096);                               \
    }                                                                           \
    __builtin_amdgcn_s_setprio(1);                                              \
    _Pragma("unroll") for (int mf = 0; mf < 4; ++mf)                            \
    _Pragma("unroll") for (int nf = 0; nf < 4; ++nf)                            \
        acc[mf][nf] = __builtin_amdgcn_mfma_f32_16x16x32_bf16(                  \
            af[mf], bfr[nf], acc[mf][nf], 0, 0, 0);                             \
    __builtin_amdgcn_s_setprio(0);                                              \
    _Pragma("unroll") for (int mf = 0; mf < 4; ++mf)                            \
        af[mf] = *(const bf16x8*)(lAr + 2048 + mf * 512);                       \
    if (DOSTAGE) {                                                              \
        bf16* dB = smem + (((T) + 3) & 3) * 16384 + 8192 + w * 512;             \
        async16(pb0 + ((T) + 3) * 32, dB);                                      \
        async16(pb1 + ((T) + 3) * 32, dB + 4096);                               \
    }                                                                           \
    __builtin_amdgcn_s_setprio(1);                                              \
    _Pragma("unroll") for (int mf = 0; mf < 4; ++mf)                            \
    _Pragma("unroll") for (int nf = 0; nf < 4; ++nf)                            \
        acc[4 + mf][nf] = __builtin_amdgcn_mfma_f32_16x16x32_bf16(              \
            af[mf], bfr[nf], acc[4 + mf][nf], 0, 0, 0);                         \
    __builtin_amdgcn_s_setprio(0);                                              \
} while (0)

__global__ __launch_bounds__(512, 2) void gemm_qk(const bf16* __restrict__ A,
                                                  const bf16* __restrict__ Bt,
                                                  const float2* __restrict__ tab,
                                                  bf16* __restrict__ qk) {
    __shared__ alignas(16) bf16 smem[65536];   // 128 KiB: 4 bufs x (A 8192 | B 8192)

    const int tid  = threadIdx.x;
    const int lane = tid & 63;
    const int w    = tid >> 6;
    const int l15  = lane & 15;
    const int quad = lane >> 4;
    const int wm   = w >> 2;       // 0..1
    const int wn   = w & 3;        // 0..3

    const int raw = blockIdx.x;                // 0..255
    const int kq  = raw >> 3;                  // 0..31
    const int mTile = (kq & 15) * 256;
    const int nTile = (2 * (raw & 7) + (kq >> 4)) * 256;

    const int sRow  = w * 16 + (lane >> 2);                       // 0..127
    const int sColE = ((lane & 3) * 8) ^ ((lane & 32) ? 16 : 0);  // elems in [0,32)
    const bf16* pa0 = A + (size_t)(mTile + sRow) * HIDDEN + sColE;
    const bf16* pa1 = pa0 + (size_t)128 * HIDDEN;
    const int n0 = qk_perm(sRow), n1 = qk_perm(sRow + 128);
    const bf16* pb0 = Bt + (size_t)(nTile + n0) * HIDDEN + sColE;
    const bf16* pb1 = Bt + (size_t)(nTile + n1) * HIDDEN + sColE;

    const int colE = (quad * 8) ^ ((l15 & 8) ? 16 : 0);
    const bf16* lA0 = smem + (wm * 128 + l15) * 32 + colE;
    const bf16* lB0 = smem + 8192 + (wn * 64 + l15) * 32 + colE;

    f32x4 acc[8][4];
#pragma unroll
    for (int i = 0; i < 8; ++i)
#pragma unroll
        for (int j = 0; j < 4; ++j) acc[i][j] = (f32x4){0.f, 0.f, 0.f, 0.f};

#pragma unroll
    for (int tt = 0; tt < 3; ++tt) {
        bf16* dA = smem + tt * 16384 + w * 512;
        async16(pa0 + tt * 32, dA);
        async16(pa1 + tt * 32, dA + 4096);
        async16(pb0 + tt * 32, dA + 8192);
        async16(pb1 + tt * 32, dA + 12288);
    }

#pragma unroll 4
    for (int t = 0; t < 60; ++t) QKV_TILE(t, 1, 8);
    QKV_TILE(60, 1, 8);
    QKV_TILE(61, 0, 8);
    QKV_TILE(62, 0, 4);
    QKV_TILE(63, 0, 0);

    // RoPE epilogue; Q region (cols < 2048) gets the softmax scale folded in.
    const float qs = (nTile < HIDDEN) ? (0.08838834764831845f * 1.4426950408889634f) : 1.0f;
    const int hbase = nTile + (wn >> 1) * 128 + (wn & 1) * 32;
#pragma unroll
    for (int mf = 0; mf < 8; ++mf)
#pragma unroll
        for (int r = 0; r < 4; ++r) {
            int row = mTile + wm * 128 + mf * 16 + quad * 4 + r;
            int s   = row & (SEQ - 1);
            float2 t0 = tab[s * 64 + (wn & 1) * 32 + l15];
            float2 t1 = tab[s * 64 + (wn & 1) * 32 + 16 + l15];
            size_t rb = (size_t)row * QKW + hbase + l15;
            float lo0 = acc[mf][0][r], hi0 = acc[mf][2][r];
            float lo1 = acc[mf][1][r], hi1 = acc[mf][3][r];
            qk[rb]      = (bf16)((lo0 * t0.x - hi0 * t0.y) * qs);
            qk[rb + 64] = (bf16)((hi0 * t0.x + lo0 * t0.y) * qs);
            qk[rb + 16] = (bf16)((lo1 * t1.x - hi1 * t1.y) * qs);
            qk[rb + 80] = (bf16)((hi1 * t1.x + lo1 * t1.y) * qs);
        }
}

// ---------------------------------------------------------------- 128x256 pipeline tile
#define OUT_TILE(T, DOSTAGE, VMN) do {                                          \
    VMW(VMN);                                                                   \
    BARX();                                                                     \
    const bf16* lAr = lA0 + ((T) & 3) * 12288;                                  \
    const bf16* lBr = lB0 + ((T) & 3) * 12288;                                  \
    bf16x8 bfr[4], af[4];                                                       \
    _Pragma("unroll") for (int nf = 0; nf < 4; ++nf)                            \
        bfr[nf] = *(const bf16x8*)(lBr + nf * 512);                             \
    _Pragma("unroll") for (int mf = 0; mf < 4; ++mf)                            \
        af[mf] = *(const bf16x8*)(lAr + mf * 512);                              \
    if (DOSTAGE) {                                                              \
        bf16* dS = smem + (((T) + 3) & 3) * 12288 + w * 512;                    \
        async16(pa0 + ((T) + 3) * 32, dS);                                      \
        async16(pb0 + ((T) + 3) * 32, dS + 4096);                               \
        async16(pb1 + ((T) + 3) * 32, dS + 8192);                               \
    }                                                                           \
    __builtin_amdgcn_s_setprio(1);                                              \
    _Pragma("unroll") for (int mf = 0; mf < 4; ++mf)                            \
    _Pragma("unroll") for (int nf = 0; nf < 4; ++nf)                            \
        acc[mf][nf] = __builtin_amdgcn_mfma_f32_16x16x32_bf16(                  \
            af[mf], bfr[nf], acc[mf][nf], 0, 0, 0);                             \
    __builtin_amdgcn_s_setprio(0);                                              \
} while (0)

#define OUT_PROLOGUE()                                                          \
    const int tid  = threadIdx.x;                                               \
    const int lane = tid & 63;                                                  \
    const int w    = tid >> 6;                                                  \
    const int l15  = lane & 15;                                                 \
    const int quad = lane >> 4;                                                 \
    const int wm   = w >> 2;                                                    \
    const int wn   = w & 3;                                                     \
    const int raw = blockIdx.x;                                                 \
    const int mTile = (raw >> 3) * 128;                                         \
    const int nTile = (raw & 7) * 256;                                          \
    const int sRow  = w * 16 + (lane >> 2);                                     \
    const int sColE = ((lane & 3) * 8) ^ ((lane & 32) ? 16 : 0);                \
    const bf16* pa0 = A + (size_t)(mTile + sRow) * HIDDEN + sColE;              \
    const bf16* pb0 = Bt + (size_t)(nTile + sRow) * HIDDEN + sColE;             \
    const bf16* pb1 = pb0 + (size_t)128 * HIDDEN;                               \
    const int colE = (quad * 8) ^ ((l15 & 8) ? 16 : 0);                         \
    const bf16* lA0 = smem + (wm * 64 + l15) * 32 + colE;                       \
    const bf16* lB0 = smem + 4096 + (wn * 64 + l15) * 32 + colE;                \
    f32x4 acc[4][4];                                                            \
    _Pragma("unroll") for (int i = 0; i < 4; ++i)                               \
    _Pragma("unroll") for (int j = 0; j < 4; ++j)                               \
        acc[i][j] = (f32x4){0.f, 0.f, 0.f, 0.f};                                \
    _Pragma("unroll") for (int tt = 0; tt < 3; ++tt) {                          \
        bf16* dS = smem + tt * 12288 + w * 512;                                 \
        async16(pa0 + tt * 32, dS);                                             \
        async16(pb0 + tt * 32, dS + 4096);                                      \
        async16(pb1 + tt * 32, dS + 8192);                                      \
    }                                                                           \
    _Pragma("unroll 4") for (int t = 0; t < 60; ++t) OUT_TILE(t, 1, 6);         \
    OUT_TILE(60, 1, 6);                                                         \
    OUT_TILE(61, 0, 6);                                                         \
    OUT_TILE(62, 0, 3);                                                         \
    OUT_TILE(63, 0, 0);

// V projection: A[4096 tok][2048] x Wv^T -> vt[feature][token] (transposed bf16 store)
__global__ __launch_bounds__(512, 2) void gemm_v(const bf16* __restrict__ A,
                                                 const bf16* __restrict__ Bt,
                                                 bf16* __restrict__ vtb) {
    __shared__ alignas(16) bf16 smem[49152];   // 96 KiB
    OUT_PROLOGUE()
#pragma unroll
    for (int mf = 0; mf < 4; ++mf)
#pragma unroll
        for (int nf = 0; nf < 4; ++nf) {
            int col_v = nTile + wn * 64 + nf * 16 + l15;        // feature
            int row0  = mTile + wm * 64 + mf * 16 + quad * 4;   // token
            bf16x4 pk;
#pragma unroll
            for (int r = 0; r < 4; ++r) pk[r] = (bf16)acc[mf][nf][r];
            *(bf16x4*)(vtb + (size_t)col_v * BS + row0) = pk;
        }
}

// final proj: out = ao * Wo^T (fp32 row-major store)
__global__ __launch_bounds__(512, 2) void gemm_out(const bf16* __restrict__ A,
                                                   const bf16* __restrict__ Bt,
                                                   float* __restrict__ C) {
    __shared__ alignas(16) bf16 smem[49152];   // 96 KiB
    OUT_PROLOGUE()
#pragma unroll
    for (int mf = 0; mf < 4; ++mf)
#pragma unroll
        for (int nf = 0; nf < 4; ++nf)
#pragma unroll
            for (int r = 0; r < 4; ++r) {
                int row = mTile + wm * 64 + mf * 16 + quad * 4 + r;
                int col = nTile + wn * 64 + nf * 16 + l15;
                C[(size_t)row * HIDDEN + col] = acc[mf][nf][r];
            }
}

// ---------------------------------------------------------------- flash attention (S^T form)
// 4 waves x 32 q-rows (QBLK=128). ASYMMETRIC buffering: K double-buffered (2x16KB),
// V single-buffered (16KB) -> 48KB LDS -> 3 blocks/CU co-resident = 12 waves/CU
// (vs 2 blocks at 64KB dbuf). Schedule per tile:
//   top:  issue K(t+1)->buf^1; VMW(8) [retire K(t); V(t)+K(t+1) in flight]; barrier; QK(t)
//   mid:  softmax; VMW(4) [retire V(t); K(t+1) in flight]; barrier; PV; barrier; issue V(t+1)
// K(t+1) overwrites the buffer last read at QK(t-1) — separated by the post-PV barrier of
// t-1. V(t+1) issues after the PV-consumed barrier. launch_bounds(256,2): VGPR free to
// land ~112 (4 waves/SIMD allowed; LDS is the 3-block limit). 512 blocks, longest-first.
__global__ __launch_bounds__(256, 2) void attn_kernel(const bf16* __restrict__ qk,
                                                      const bf16* __restrict__ vt,
                                                      bf16* __restrict__ ao) {
    __shared__ bf16 Kls[2][64 * 128];   // 32 KB: [j][d], 16B chunk c of row j at c^(j&7)
    __shared__ bf16 Vls[128 * 64];      // 16 KB: [d][s], swizzled same

    const int tid  = threadIdx.x;
    const int lane = tid & 63;
    const int w    = tid >> 6;          // 0..3
    const int l15  = lane & 15;
    const int quad = lane >> 4;
    const int bid  = blockIdx.x;
    const int qb2  = 15 - (bid >> 5);   // longest blocks dispatch first
    const int bh   = bid & 31;
    const int b    = bh >> 4;
    const int h    = bh & 15;
    const int qbase = qb2 * 128;
    const int nt    = 2 * qb2 + 2;
    const size_t seq0 = (size_t)b * SEQ;

    // Q fragments: 2 q-subtiles of 16 rows each (pre-scaled by gemm_qk)
    bf16x8 qf[2][4];
#pragma unroll
    for (int qs = 0; qs < 2; ++qs) {
        const bf16* qp = qk + (seq0 + qbase + w * 32 + qs * 16 + l15) * QKW + h * HDIM + quad * 8;
#pragma unroll
        for (int ks = 0; ks < 4; ++ks) qf[qs][ks] = *(const bf16x8*)(qp + ks * 32);
    }
#pragma unroll
    for (int qs = 0; qs < 2; ++qs)
#pragma unroll
        for (int ks = 0; ks < 4; ++ks)
            asm volatile("" :: "v"(*(const f32x4*)&qf[qs][ks]));   // pin Q wait to preheader

    f32x4 o[8][2];
#pragma unroll
    for (int i = 0; i < 8; ++i)
#pragma unroll
        for (int qs = 0; qs < 2; ++qs) o[i][qs] = (f32x4){0.f, 0.f, 0.f, 0.f};
    float m_s[2] = {-3e38f, -3e38f}, l_s[2] = {0.f, 0.f};
    int qg[2];
#pragma unroll
    for (int qs = 0; qs < 2; ++qs) qg[qs] = qbase + w * 32 + qs * 16 + l15;

    const int krow = lane >> 4;
    const int kp   = lane & 15;
    const int vrow = lane >> 3;
    const int vp   = lane & 7;
    const int sw   = l15 & 7;

    // ---- staging sources: uniform SGPR base + 32-bit lane offsets (4 K + 4 V per wave) ----
    const bf16* qksrc = qk + seq0 * QKW + HIDDEN + h * HDIM;          // uniform
    const bf16* vtsrc = vt + (size_t)h * HDIM * BS + seq0;            // uniform
    int koff[4], voff[4];
#pragma unroll
    for (int i = 0; i < 4; ++i) {
        int c = w * 4 + i;                 // 0..15
        int j = c * 4 + krow;              // K row 0..63
        int c2 = (kp & 8) | ((kp & 7) ^ (j & 7));
        koff[i] = j * QKW + c2 * 8;
        int d = c * 8 + vrow;              // V feature row 0..127
        int cv = vp ^ (d & 7);
        voff[i] = d * BS + cv * 8;
    }

    // ---- hoisted LDS read bases; BUF/ni/n2 variation -> ds_read immediates ----
    const bf16* kbase[4];
#pragma unroll
    for (int ks = 0; ks < 4; ++ks)
        kbase[ks] = &Kls[0][l15 * 128 + (((ks * 4 + quad) ^ sw) << 3)];
    const bf16* vbase[4];
#pragma unroll
    for (int ni = 0; ni < 4; ++ni)
        vbase[ni] = &Vls[l15 * 64 + ((((ni * 2 + (quad >> 1)) ^ sw) << 3) + (quad & 1) * 4)];

#define STAGE_K(T, BUF) do {                                                     \
        _Pragma("unroll") for (int i = 0; i < 4; ++i)                            \
            async16(qksrc + (size_t)((T) * 64) * QKW + koff[i],                  \
                    &Kls[BUF][(w * 4 + i) * 512]);                               \
    } while (0)
#define STAGE_V(T) do {                                                          \
        _Pragma("unroll") for (int i = 0; i < 4; ++i)                            \
            async16(vtsrc + (T) * 64 + voff[i],                                  \
                    &Vls[(w * 4 + i) * 512]);                                    \
    } while (0)

    STAGE_K(0, 0);
    STAGE_V(0);

    for (int t = 0; t < nt; ++t) {
        const int kb = t * 64;
        if (t + 1 < nt) { STAGE_K(t + 1, (t + 1) & 1); VMW(8); }
        else            { VMW(4); }
        BARX();                              // K(t) visible block-wide

        // ---- QK^T from Kls[t&1] ----
        f32x4 sa[4][2];
#pragma unroll
        for (int ni = 0; ni < 4; ++ni)
#pragma unroll
            for (int qs = 0; qs < 2; ++qs) sa[ni][qs] = (f32x4){0.f, 0.f, 0.f, 0.f};
        __builtin_amdgcn_s_setprio(1);
#pragma unroll
        for (int ni = 0; ni < 4; ++ni)
#pragma unroll
            for (int ks = 0; ks < 4; ++ks) {
                bf16x8 kf = *(const bf16x8*)(kbase[ks] + (t & 1) * 8192 + ni * 2048);
                sa[ni][0] = __builtin_amdgcn_mfma_f32_16x16x32_bf16(kf, qf[0][ks], sa[ni][0], 0, 0, 0);
                sa[ni][1] = __builtin_amdgcn_mfma_f32_16x16x32_bf16(kf, qf[1][ks], sa[ni][1], 0, 0, 0);
            }
        __builtin_amdgcn_s_setprio(0);

        // ---- softmax (lane-scalar state, defer-max) ----
        const bool diag = (t >= nt - 2);
        b4u pb[4][2];
#pragma unroll
        for (int qs = 0; qs < 2; ++qs) {
            float rmax = -3e38f;
#pragma unroll
            for (int ni = 0; ni < 4; ++ni)
#pragma unroll
                for (int r = 0; r < 4; ++r) {
                    float sv = sa[ni][qs][r];
                    if (diag && (kb + ni * 16 + quad * 4 + r > qg[qs])) sv = -1e30f;
                    sa[ni][qs][r] = sv;
                    rmax = fmaxf(rmax, sv);
                }
            rmax = fmaxf(rmax, __shfl_xor(rmax, 16));
            rmax = fmaxf(rmax, __shfl_xor(rmax, 32));
            if (__ballot(rmax > m_s[qs] + 8.f) != 0ull) {
                float mn = fmaxf(m_s[qs], rmax);
                float al = ex2(m_s[qs] - mn);
                m_s[qs] = mn; l_s[qs] *= al;
#pragma unroll
                for (int n2 = 0; n2 < 8; ++n2)
#pragma unroll
                    for (int r = 0; r < 4; ++r) o[n2][qs][r] *= al;
            }
            float rsum = 0.f;
#pragma unroll
            for (int ni = 0; ni < 4; ++ni)
#pragma unroll
                for (int r = 0; r < 4; ++r) {
                    float e = ex2(sa[ni][qs][r] - m_s[qs]);
                    rsum += e;
                    pb[ni][qs].h[r] = (bf16)e;
                }
            rsum += __shfl_xor(rsum, 16);
            rsum += __shfl_xor(rsum, 32);
            l_s[qs] += rsum;
        }

        if (t + 1 < nt) { VMW(4); }          // retire own V(t); K(t+1) stays in flight
        else            { VMW(0); }
        BARX();                              // V(t) visible block-wide

        // ---- PV ----
        __builtin_amdgcn_s_setprio(1);
#pragma unroll
        for (int n2 = 0; n2 < 8; ++n2)
#pragma unroll
            for (int ni = 0; ni < 4; ++ni) {
                b4u vf;
                vf.h = *(const bf16x4*)(vbase[ni] + n2 * 1024);
                o[n2][0] = __builtin_amdgcn_mfma_f32_16x16x16bf16_1k(vf.s, pb[ni][0].s, o[n2][0], 0, 0, 0);
                o[n2][1] = __builtin_amdgcn_mfma_f32_16x16x16bf16_1k(vf.s, pb[ni][1].s, o[n2][1], 0, 0, 0);
            }
        __builtin_amdgcn_s_setprio(0);
        BARX();                              // all waves done reading Vls
        if (t + 1 < nt) STAGE_V(t + 1);      // overwrite Vls; lands under next QK+softmax
    }
#undef STAGE_K
#undef STAGE_V

#pragma unroll
    for (int qs = 0; qs < 2; ++qs) {
        const float inv = 1.0f / l_s[qs];
        bf16* op = ao + (seq0 + qg[qs]) * HIDDEN + h * HDIM + quad * 4;
#pragma unroll
        for (int n2 = 0; n2 < 8; ++n2) {
            bf16x4 pk;
#pragma unroll
            for (int r = 0; r < 4; ++r) pk[r] = (bf16)(o[n2][qs][r] * inv);
            *(bf16x4*)(op + n2 * 16) = pk;
        }
    }
}

// ---------------------------------------------------------------- launch
extern "C" void kernel_launch(void* const* d_in, const int* in_sizes, int n_in,
                              void* d_out, int out_size, void* d_ws, size_t ws_size,
                              hipStream_t stream) {
    const float* hs = (const float*)d_in[0];
    const float* Wq = (const float*)d_in[1];
    const float* Wk = (const float*)d_in[2];
    const float* Wv = (const float*)d_in[3];
    const float* Wo = (const float*)d_in[4];
    const int* pos  = (const int*)d_in[6];
    float* out = (float*)d_out;

    bf16* hs_b = (bf16*)d_ws;                               //  8,388,608 el
    bf16* wqkv = hs_b + (size_t)8388608;                    // 12,582,912 el [6144][2048]
    bf16* wo_b = wqkv + (size_t)12582912;                   //  4,194,304 el
    bf16* qkb  = wo_b + (size_t)4194304;                    // 16,777,216 el [4096][4096]
    bf16* vtb  = qkb + (size_t)16777216;                    //  8,388,608 el [2048][4096]
    bf16* ao   = vtb + (size_t)8388608;                     //  8,388,608 el
    float2* tab = (float2*)ao;  // 1 MB, consumed by gemm_qk BEFORE attn writes ao

    cast_all<<<25088, 256, 0, stream>>>(hs, Wq, Wk, Wv, Wo, pos, hs_b, wqkv, wo_b, tab);
    gemm_qk<<<256, 512, 0, stream>>>(hs_b, wqkv, tab, qkb);
    gemm_v<<<256, 512, 0, stream>>>(hs_b, wqkv + (size_t)8388608, vtb);
    attn_kernel<<<512, 256, 0, stream>>>(qkb, vtb, ao);
    gemm_out<<<256, 512, 0, stream>>>(ao, wo_b, out);
}

// Round 10
// 359.049 us; speedup vs baseline: 1.4417x; 1.0743x over previous
//
#include <hip/hip_runtime.h>
#include <cstdint>
#include <cstddef>

typedef __bf16 bf16;
typedef __bf16 bf16x4 __attribute__((ext_vector_type(4)));
typedef __bf16 bf16x8 __attribute__((ext_vector_type(8)));
typedef float  f32x4  __attribute__((ext_vector_type(4)));
typedef short  s16x4  __attribute__((ext_vector_type(4)));

#define HIDDEN 2048
#define NHEADS 16
#define HDIM   128
#define BSZ    2
#define SEQ    2048
#define BS     (BSZ*SEQ)     /* 4096 rows */
#define QKW    (2*HIDDEN)    /* 4096: Q|K concat width */

union b4u { bf16x4 h; s16x4 s; };

// async global->LDS, 16B per lane. LDS dest = wave-uniform base + lane*16.
__device__ __forceinline__ void async16(const bf16* g, bf16* l) {
    __builtin_amdgcn_global_load_lds(
        (const __attribute__((address_space(1))) unsigned int*)g,
        (__attribute__((address_space(3))) unsigned int*)l, 16, 0, 0);
}

#define BARX()  asm volatile("s_barrier" ::: "memory")
#define VMW(N)  asm volatile("s_waitcnt vmcnt(" #N ")" ::: "memory")

// raw v_exp_f32: exp2 is the native op, skip OCML fixups (args are <= 8, large-neg -> 0)
__device__ __forceinline__ float ex2(float x) {
    float r; asm("v_exp_f32 %0, %1" : "=v"(r) : "v"(x)); return r;
}

// ---------------------------------------------------------------- fused casts + rope table
__global__ __launch_bounds__(256) void cast_all(const float* __restrict__ hs,
                                                const float* __restrict__ Wq,
                                                const float* __restrict__ Wk,
                                                const float* __restrict__ Wv,
                                                const float* __restrict__ Wo,
                                                const int* __restrict__ pos,
                                                bf16* __restrict__ hs_b,
                                                bf16* __restrict__ wqkv,
                                                bf16* __restrict__ wo_b,
                                                float2* __restrict__ tab) {
    int i = blockIdx.x * 256 + threadIdx.x;
    if (i >= 6291456) {                       // rope table region
        int j = i - 6291456;                  // 0..131071
        int s = j >> 6, p = j & 63;
        float t = (float)pos[s];
        float inv = expf(-(float)(2 * p) * (9.2103403719761836f / 128.0f));
        float sn, cs;
        sincosf(t * inv, &sn, &cs);
        tab[j] = make_float2(cs, sn);
        return;
    }
    const float* src; bf16* dst; int off;
    if (i < 2097152) { src = hs; dst = hs_b; off = i; }
    else {
        int j = i - 2097152;
        int r = j >> 20;
        off = j & 1048575;
        if      (r == 0) { src = Wq; dst = wqkv; }
        else if (r == 1) { src = Wk; dst = wqkv + (size_t)4194304; }
        else if (r == 2) { src = Wv; dst = wqkv + (size_t)8388608; }
        else             { src = Wo; dst = wo_b; }
    }
    const float4 v = ((const float4*)src)[off];
    bf16x4 o;
    o.x = (bf16)v.x; o.y = (bf16)v.y; o.z = (bf16)v.z; o.w = (bf16)v.w;
    ((bf16x4*)dst)[off] = o;
}

// ---------------------------------------------------------------- Q|K GEMM + RoPE
// 256x256 tile, BK=32, 512 thr (8 waves 2M x 4N), ring-4 LDS, counted vmcnt,
// st_16x32 swizzle, setprio. Grid 256 = EXACTLY one full round on 256 CUs.
// Q region written PRE-SCALED by 1/sqrt(128)*log2(e) so attn's S is exp2-domain.
__device__ __forceinline__ int qk_perm(int n) {
    int wl = n >> 6, j = n & 63;
    return ((wl >> 1) << 7) | ((j >> 5) << 6) | ((wl & 1) << 5) | (j & 31);
}

#define QKV_TILE(T, DOSTAGE, VMN) do {                                          \
    VMW(VMN);                                                                   \
    BARX();                                                                     \
    const bf16* lAr = lA0 + ((T) & 3) * 16384;                                  \
    const bf16* lBr = lB0 + ((T) & 3) * 16384;                                  \
    bf16x8 bfr[4], af[4];                                                       \
    _Pragma("unroll") for (int nf = 0; nf < 4; ++nf)                            \
        bfr[nf] = *(const bf16x8*)(lBr + nf * 512);                             \
    _Pragma("unroll") for (int mf = 0; mf < 4; ++mf)                            \
        af[mf] = *(const bf16x8*)(lAr + mf * 512);                              \
    if (DOSTAGE) {                                                              \
        bf16* dA = smem + (((T) + 3) & 3) * 16384 + w * 512;                    \
        async16(pa0 + ((T) + 3) * 32, dA);                                      \
        async16(pa1 + ((T) + 3) * 32, dA + 4096);                               \
    }                                                                           \
    __builtin_amdgcn_s_setprio(1);                                              \
    _Pragma("unroll") for (int mf = 0; mf < 4; ++mf)                            \
    _Pragma("unroll") for (int nf = 0; nf < 4; ++nf)                            \
        acc[mf][nf] = __builtin_amdgcn_mfma_f32_16x16x32_bf16(                  \
            af[mf], bfr[nf], acc[mf][nf], 0, 0, 0);                             \
    __builtin_amdgcn_s_setprio(0);                                              \
    _Pragma("unroll") for (int mf = 0; mf < 4; ++mf)                            \
        af[mf] = *(const bf16x8*)(lAr + 2048 + mf * 512);                       \
    if (DOSTAGE) {                                                              \
        bf16* dB = smem + (((T) + 3) & 3) * 16384 + 8192 + w * 512;             \
        async16(pb0 + ((T) + 3) * 32, dB);                                      \
        async16(pb1 + ((T) + 3) * 32, dB + 4096);                               \
    }                                                                           \
    __builtin_amdgcn_s_setprio(1);                                              \
    _Pragma("unroll") for (int mf = 0; mf < 4; ++mf)                            \
    _Pragma("unroll") for (int nf = 0; nf < 4; ++nf)                            \
        acc[4 + mf][nf] = __builtin_amdgcn_mfma_f32_16x16x32_bf16(              \
            af[mf], bfr[nf], acc[4 + mf][nf], 0, 0, 0);                         \
    __builtin_amdgcn_s_setprio(0);                                              \
} while (0)

__global__ __launch_bounds__(512, 2) void gemm_qk(const bf16* __restrict__ A,
                                                  const bf16* __restrict__ Bt,
                                                  const float2* __restrict__ tab,
                                                  bf16* __restrict__ qk) {
    __shared__ alignas(16) bf16 smem[65536];   // 128 KiB: 4 bufs x (A 8192 | B 8192)

    const int tid  = threadIdx.x;
    const int lane = tid & 63;
    const int w    = tid >> 6;
    const int l15  = lane & 15;
    const int quad = lane >> 4;
    const int wm   = w >> 2;       // 0..1
    const int wn   = w & 3;        // 0..3

    const int raw = blockIdx.x;                // 0..255
    const int kq  = raw >> 3;                  // 0..31
    const int mTile = (kq & 15) * 256;
    const int nTile = (2 * (raw & 7) + (kq >> 4)) * 256;

    const int sRow  = w * 16 + (lane >> 2);                       // 0..127
    const int sColE = ((lane & 3) * 8) ^ ((lane & 32) ? 16 : 0);  // elems in [0,32)
    const bf16* pa0 = A + (size_t)(mTile + sRow) * HIDDEN + sColE;
    const bf16* pa1 = pa0 + (size_t)128 * HIDDEN;
    const int n0 = qk_perm(sRow), n1 = qk_perm(sRow + 128);
    const bf16* pb0 = Bt + (size_t)(nTile + n0) * HIDDEN + sColE;
    const bf16* pb1 = Bt + (size_t)(nTile + n1) * HIDDEN + sColE;

    const int colE = (quad * 8) ^ ((l15 & 8) ? 16 : 0);
    const bf16* lA0 = smem + (wm * 128 + l15) * 32 + colE;
    const bf16* lB0 = smem + 8192 + (wn * 64 + l15) * 32 + colE;

    f32x4 acc[8][4];
#pragma unroll
    for (int i = 0; i < 8; ++i)
#pragma unroll
        for (int j = 0; j < 4; ++j) acc[i][j] = (f32x4){0.f, 0.f, 0.f, 0.f};

#pragma unroll
    for (int tt = 0; tt < 3; ++tt) {
        bf16* dA = smem + tt * 16384 + w * 512;
        async16(pa0 + tt * 32, dA);
        async16(pa1 + tt * 32, dA + 4096);
        async16(pb0 + tt * 32, dA + 8192);
        async16(pb1 + tt * 32, dA + 12288);
    }

#pragma unroll 4
    for (int t = 0; t < 60; ++t) QKV_TILE(t, 1, 8);
    QKV_TILE(60, 1, 8);
    QKV_TILE(61, 0, 8);
    QKV_TILE(62, 0, 4);
    QKV_TILE(63, 0, 0);

    // RoPE epilogue; Q region (cols < 2048) gets the softmax scale folded in.
    const float qs = (nTile < HIDDEN) ? (0.08838834764831845f * 1.4426950408889634f) : 1.0f;
    const int hbase = nTile + (wn >> 1) * 128 + (wn & 1) * 32;
#pragma unroll
    for (int mf = 0; mf < 8; ++mf)
#pragma unroll
        for (int r = 0; r < 4; ++r) {
            int row = mTile + wm * 128 + mf * 16 + quad * 4 + r;
            int s   = row & (SEQ - 1);
            float2 t0 = tab[s * 64 + (wn & 1) * 32 + l15];
            float2 t1 = tab[s * 64 + (wn & 1) * 32 + 16 + l15];
            size_t rb = (size_t)row * QKW + hbase + l15;
            float lo0 = acc[mf][0][r], hi0 = acc[mf][2][r];
            float lo1 = acc[mf][1][r], hi1 = acc[mf][3][r];
            qk[rb]      = (bf16)((lo0 * t0.x - hi0 * t0.y) * qs);
            qk[rb + 64] = (bf16)((hi0 * t0.x + lo0 * t0.y) * qs);
            qk[rb + 16] = (bf16)((lo1 * t1.x - hi1 * t1.y) * qs);
            qk[rb + 80] = (bf16)((hi1 * t1.x + lo1 * t1.y) * qs);
        }
}

// ---------------------------------------------------------------- 128x256 pipeline tile
#define OUT_TILE(T, DOSTAGE, VMN) do {                                          \
    VMW(VMN);                                                                   \
    BARX();                                                                     \
    const bf16* lAr = lA0 + ((T) & 3) * 12288;                                  \
    const bf16* lBr = lB0 + ((T) & 3) * 12288;                                  \
    bf16x8 bfr[4], af[4];                                                       \
    _Pragma("unroll") for (int nf = 0; nf < 4; ++nf)                            \
        bfr[nf] = *(const bf16x8*)(lBr + nf * 512);                             \
    _Pragma("unroll") for (int mf = 0; mf < 4; ++mf)                            \
        af[mf] = *(const bf16x8*)(lAr + mf * 512);                              \
    if (DOSTAGE) {                                                              \
        bf16* dS = smem + (((T) + 3) & 3) * 12288 + w * 512;                    \
        async16(pa0 + ((T) + 3) * 32, dS);                                      \
        async16(pb0 + ((T) + 3) * 32, dS + 4096);                               \
        async16(pb1 + ((T) + 3) * 32, dS + 8192);                               \
    }                                                                           \
    __builtin_amdgcn_s_setprio(1);                                              \
    _Pragma("unroll") for (int mf = 0; mf < 4; ++mf)                            \
    _Pragma("unroll") for (int nf = 0; nf < 4; ++nf)                            \
        acc[mf][nf] = __builtin_amdgcn_mfma_f32_16x16x32_bf16(                  \
            af[mf], bfr[nf], acc[mf][nf], 0, 0, 0);                             \
    __builtin_amdgcn_s_setprio(0);                                              \
} while (0)

#define OUT_PROLOGUE()                                                          \
    const int tid  = threadIdx.x;                                               \
    const int lane = tid & 63;                                                  \
    const int w    = tid >> 6;                                                  \
    const int l15  = lane & 15;                                                 \
    const int quad = lane >> 4;                                                 \
    const int wm   = w >> 2;                                                    \
    const int wn   = w & 3;                                                     \
    const int raw = blockIdx.x;                                                 \
    const int mTile = (raw >> 3) * 128;                                         \
    const int nTile = (raw & 7) * 256;                                          \
    const int sRow  = w * 16 + (lane >> 2);                                     \
    const int sColE = ((lane & 3) * 8) ^ ((lane & 32) ? 16 : 0);                \
    const bf16* pa0 = A + (size_t)(mTile + sRow) * HIDDEN + sColE;              \
    const bf16* pb0 = Bt + (size_t)(nTile + sRow) * HIDDEN + sColE;             \
    const bf16* pb1 = pb0 + (size_t)128 * HIDDEN;                               \
    const int colE = (quad * 8) ^ ((l15 & 8) ? 16 : 0);                         \
    const bf16* lA0 = smem + (wm * 64 + l15) * 32 + colE;                       \
    const bf16* lB0 = smem + 4096 + (wn * 64 + l15) * 32 + colE;                \
    f32x4 acc[4][4];                                                            \
    _Pragma("unroll") for (int i = 0; i < 4; ++i)                               \
    _Pragma("unroll") for (int j = 0; j < 4; ++j)                               \
        acc[i][j] = (f32x4){0.f, 0.f, 0.f, 0.f};                                \
    _Pragma("unroll") for (int tt = 0; tt < 3; ++tt) {                          \
        bf16* dS = smem + tt * 12288 + w * 512;                                 \
        async16(pa0 + tt * 32, dS);                                             \
        async16(pb0 + tt * 32, dS + 4096);                                      \
        async16(pb1 + tt * 32, dS + 8192);                                      \
    }                                                                           \
    _Pragma("unroll 4") for (int t = 0; t < 60; ++t) OUT_TILE(t, 1, 6);         \
    OUT_TILE(60, 1, 6);                                                         \
    OUT_TILE(61, 0, 6);                                                         \
    OUT_TILE(62, 0, 3);                                                         \
    OUT_TILE(63, 0, 0);

// V projection: A[4096 tok][2048] x Wv^T -> vt[feature][token] (transposed bf16 store)
__global__ __launch_bounds__(512, 2) void gemm_v(const bf16* __restrict__ A,
                                                 const bf16* __restrict__ Bt,
                                                 bf16* __restrict__ vtb) {
    __shared__ alignas(16) bf16 smem[49152];   // 96 KiB
    OUT_PROLOGUE()
#pragma unroll
    for (int mf = 0; mf < 4; ++mf)
#pragma unroll
        for (int nf = 0; nf < 4; ++nf) {
            int col_v = nTile + wn * 64 + nf * 16 + l15;        // feature
            int row0  = mTile + wm * 64 + mf * 16 + quad * 4;   // token
            bf16x4 pk;
#pragma unroll
            for (int r = 0; r < 4; ++r) pk[r] = (bf16)acc[mf][nf][r];
            *(bf16x4*)(vtb + (size_t)col_v * BS + row0) = pk;
        }
}

// final proj: out = ao * Wo^T (fp32 row-major store)
__global__ __launch_bounds__(512, 2) void gemm_out(const bf16* __restrict__ A,
                                                   const bf16* __restrict__ Bt,
                                                   float* __restrict__ C) {
    __shared__ alignas(16) bf16 smem[49152];   // 96 KiB
    OUT_PROLOGUE()
#pragma unroll
    for (int mf = 0; mf < 4; ++mf)
#pragma unroll
        for (int nf = 0; nf < 4; ++nf)
#pragma unroll
            for (int r = 0; r < 4; ++r) {
                int row = mTile + wm * 64 + mf * 16 + quad * 4 + r;
                int col = nTile + wn * 64 + nf * 16 + l15;
                C[(size_t)row * HIDDEN + col] = acc[mf][nf][r];
            }
}

// ---------------------------------------------------------------- flash attention (S^T form)
// 8 waves x QBLK=128, 512 blocks ALL co-resident (2 blocks/CU, 64KB LDS each), paired so
// each CU's two blocks sum to a constant 34 tiles. Q pre-scaled (exp2 domain). Dbuf K/V
// with counted vmcnt; hoisted LDS read bases (all variation in ds_read immediates);
// raw v_exp_f32; defer-max (T13): skip o-rescale unless tile max grew > 8.
// SESSION-BEST attn config (85.4 us, VGPR 64, occ 30%): do NOT force occupancy via
// launch_bounds (R6: (256,4) capped VGPR at 64-with-spill, ~300MB scratch, 230 us);
// do NOT single-buffer V (R7/R8: +10-17 us); do NOT halve waves/block (R5: idle CU).
__global__ __launch_bounds__(512, 4) void attn_kernel(const bf16* __restrict__ qk,
                                                      const bf16* __restrict__ vt,
                                                      bf16* __restrict__ ao) {
    __shared__ bf16 Kls[2][64 * 128];   // [j][d], 16B chunk c of row j at c^(j&7)
    __shared__ bf16 Vls[2][128 * 64];   // [d][s], swizzled same

    const int tid  = threadIdx.x;
    const int lane = tid & 63;
    const int w    = tid >> 6;          // 0..7
    const int l15  = lane & 15;
    const int quad = lane >> 4;
    const int bid  = blockIdx.x;
    // balanced pairing: first 256 bids qb2 = 15-(idx>>5), next 256 qb2 = idx>>5.
    // CU c gets bids {c, c+256} (round-robin heuristic) -> per-CU tiles = 34 const.
    const int half = bid >> 8;
    const int idx  = bid & 255;
    const int qb2  = half ? (idx >> 5) : 15 - (idx >> 5);
    const int bh   = idx & 31;
    const int b    = bh >> 4;
    const int h    = bh & 15;
    const int qbase = qb2 * 128;
    const int nt    = 2 * qb2 + 2;      // always even
    const size_t seq0 = (size_t)b * SEQ;

    // Q fragments (pre-scaled by gemm_qk)
    bf16x8 qf[4];
    {
        const bf16* qp = qk + (seq0 + qbase + w * 16 + l15) * QKW + h * HDIM + quad * 8;
#pragma unroll
        for (int ks = 0; ks < 4; ++ks) qf[ks] = *(const bf16x8*)(qp + ks * 32);
    }
#pragma unroll
    for (int ks = 0; ks < 4; ++ks)
        asm volatile("" :: "v"(*(const f32x4*)&qf[ks]));   // pin Q wait to preheader

    f32x4 o[8];
#pragma unroll
    for (int i = 0; i < 8; ++i) o[i] = (f32x4){0.f, 0.f, 0.f, 0.f};
    float m_s = -3e38f, l_s = 0.f;
    const int qg = qbase + w * 16 + l15;

    const int krow = lane >> 4;
    const int kp   = lane & 15;
    const int vrow = lane >> 3;
    const int vp   = lane & 7;
    const int sw   = l15 & 7;

    // ---- staging sources: uniform SGPR base + 32-bit lane offsets ----
    const bf16* qksrc = qk + seq0 * QKW + HIDDEN + h * HDIM;          // uniform
    const bf16* vtsrc = vt + (size_t)h * HDIM * BS + seq0;            // uniform
    int koff[2], voff[2];
#pragma unroll
    for (int i = 0; i < 2; ++i) {
        int c = w * 2 + i;
        int j = c * 4 + krow;
        int c2 = (kp & 8) | ((kp & 7) ^ (j & 7));
        koff[i] = j * QKW + c2 * 8;
        int d = c * 8 + vrow;
        int cv = vp ^ (d & 7);
        voff[i] = d * BS + cv * 8;
    }

    // ---- hoisted LDS read bases (buffer 0); BUF/ni/n2 variation -> ds offsets ----
    const bf16* kbase[4];
#pragma unroll
    for (int ks = 0; ks < 4; ++ks)
        kbase[ks] = &Kls[0][l15 * 128 + (((ks * 4 + quad) ^ sw) << 3)];
    const bf16* vbase[4];
#pragma unroll
    for (int ni = 0; ni < 4; ++ni)
        vbase[ni] = &Vls[0][l15 * 64 + ((((ni * 2 + (quad >> 1)) ^ sw) << 3) + (quad & 1) * 4)];

#define ATTN_STAGE(T, BUF) do {                                                  \
        const int kb_ = (T) * 64;                                                \
        _Pragma("unroll") for (int i = 0; i < 2; ++i)                            \
            async16(qksrc + (size_t)kb_ * QKW + koff[i],                         \
                    &Kls[BUF][(w * 2 + i) * 512]);                               \
        _Pragma("unroll") for (int i = 0; i < 2; ++i)                            \
            async16(vtsrc + kb_ + voff[i],                                       \
                    &Vls[BUF][(w * 2 + i) * 512]);                               \
    } while (0)

#define ATTN_TILE(T, BUF) do {                                                   \
        if ((T) + 1 < nt) { ATTN_STAGE((T) + 1, (BUF) ^ 1); VMW(4); }            \
        else              { VMW(0); }                                            \
        BARX();                                                                  \
        const int kb = (T) * 64;                                                 \
        f32x4 sa[4];                                                             \
        _Pragma("unroll") for (int ni = 0; ni < 4; ++ni)                         \
            sa[ni] = (f32x4){0.f, 0.f, 0.f, 0.f};                                \
        _Pragma("unroll") for (int ni = 0; ni < 4; ++ni)                         \
        _Pragma("unroll") for (int ks = 0; ks < 4; ++ks) {                       \
            bf16x8 kf = *(const bf16x8*)(kbase[ks] + (BUF) * 8192 + ni * 2048);  \
            sa[ni] = __builtin_amdgcn_mfma_f32_16x16x32_bf16(kf, qf[ks], sa[ni], 0, 0, 0); \
        }                                                                        \
        float rmax = -3e38f;                                                     \
        const bool diag = ((T) >= nt - 2);                                       \
        _Pragma("unroll") for (int ni = 0; ni < 4; ++ni)                         \
        _Pragma("unroll") for (int r = 0; r < 4; ++r) {                          \
            float sv = sa[ni][r];                                                \
            if (diag && (kb + ni * 16 + quad * 4 + r > qg)) sv = -1e30f;         \
            sa[ni][r] = sv;                                                      \
            rmax = fmaxf(rmax, sv);                                              \
        }                                                                        \
        rmax = fmaxf(rmax, __shfl_xor(rmax, 16));                                \
        rmax = fmaxf(rmax, __shfl_xor(rmax, 32));                                \
        if (__ballot(rmax > m_s + 8.f) != 0ull) {                                \
            float mn = fmaxf(m_s, rmax);                                         \
            float al = ex2(m_s - mn);                                            \
            m_s = mn; l_s *= al;                                                 \
            _Pragma("unroll") for (int n2 = 0; n2 < 8; ++n2)                     \
            _Pragma("unroll") for (int r = 0; r < 4; ++r) o[n2][r] *= al;        \
        }                                                                        \
        float rsum = 0.f;                                                        \
        b4u pb[4];                                                               \
        _Pragma("unroll") for (int ni = 0; ni < 4; ++ni)                         \
        _Pragma("unroll") for (int r = 0; r < 4; ++r) {                          \
            float e = ex2(sa[ni][r] - m_s);                                      \
            rsum += e;                                                           \
            pb[ni].h[r] = (bf16)e;                                               \
        }                                                                        \
        rsum += __shfl_xor(rsum, 16);                                            \
        rsum += __shfl_xor(rsum, 32);                                            \
        l_s += rsum;                                                             \
        _Pragma("unroll") for (int n2 = 0; n2 < 8; ++n2)                         \
        _Pragma("unroll") for (int ni = 0; ni < 4; ++ni) {                       \
            b4u vf;                                                              \
            vf.h = *(const bf16x4*)(vbase[ni] + (BUF) * 8192 + n2 * 1024);       \
            o[n2] = __builtin_amdgcn_mfma_f32_16x16x16bf16_1k(vf.s, pb[ni].s, o[n2], 0, 0, 0); \
        }                                                                        \
        BARX();                                                                  \
    } while (0)

    ATTN_STAGE(0, 0);
    for (int t = 0; t < nt; t += 2) {
        ATTN_TILE(t, 0);
        ATTN_TILE(t + 1, 1);
    }
#undef ATTN_TILE
#undef ATTN_STAGE

    const float inv = 1.0f / l_s;
    bf16* op = ao + (seq0 + qg) * HIDDEN + h * HDIM + quad * 4;
#pragma unroll
    for (int n2 = 0; n2 < 8; ++n2) {
        bf16x4 pk;
#pragma unroll
        for (int r = 0; r < 4; ++r) pk[r] = (bf16)(o[n2][r] * inv);
        *(bf16x4*)(op + n2 * 16) = pk;
    }
}

// ---------------------------------------------------------------- launch
extern "C" void kernel_launch(void* const* d_in, const int* in_sizes, int n_in,
                              void* d_out, int out_size, void* d_ws, size_t ws_size,
                              hipStream_t stream) {
    const float* hs = (const float*)d_in[0];
    const float* Wq = (const float*)d_in[1];
    const float* Wk = (const float*)d_in[2];
    const float* Wv = (const float*)d_in[3];
    const float* Wo = (const float*)d_in[4];
    const int* pos  = (const int*)d_in[6];
    float* out = (float*)d_out;

    bf16* hs_b = (bf16*)d_ws;                               //  8,388,608 el
    bf16* wqkv = hs_b + (size_t)8388608;                    // 12,582,912 el [6144][2048]
    bf16* wo_b = wqkv + (size_t)12582912;                   //  4,194,304 el
    bf16* qkb  = wo_b + (size_t)4194304;                    // 16,777,216 el [4096][4096]
    bf16* vtb  = qkb + (size_t)16777216;                    //  8,388,608 el [2048][4096]
    bf16* ao   = vtb + (size_t)8388608;                     //  8,388,608 el
    float2* tab = (float2*)ao;  // 1 MB, consumed by gemm_qk BEFORE attn writes ao

    cast_all<<<25088, 256, 0, stream>>>(hs, Wq, Wk, Wv, Wo, pos, hs_b, wqkv, wo_b, tab);
    gemm_qk<<<256, 512, 0, stream>>>(hs_b, wqkv, tab, qkb);
    gemm_v<<<256, 512, 0, stream>>>(hs_b, wqkv + (size_t)8388608, vtb);
    attn_kernel<<<512, 512, 0, stream>>>(qkb, vtb, ao);
    gemm_out<<<256, 512, 0, stream>>>(ao, wo_b, out);
}